// Round 3
// baseline (611.949 us; speedup 1.0000x reference)
//
#include <hip/hip_runtime.h>
#include <cstdint>
#include <cstddef>

#define B_SZ 8
#define N1 4096
#define N2 256
#define LTOT 4352          // N1 + N2
#define DIMD 1024
#define HEADS 16
#define DH 64
#define MKV (B_SZ * LTOT)  // 34816
#define KSPLIT 2
#define KTILES (LTOT / 128)        // 34
#define KT_PER (KTILES / KSPLIT)   // 17

typedef _Float16 f16;
typedef f16 f16x4_t __attribute__((ext_vector_type(4)));
typedef f16 f16x8_t __attribute__((ext_vector_type(8)));
typedef float f32x4_t __attribute__((ext_vector_type(4)));

// async global -> LDS, 16B per lane. LDS dest is wave-uniform base + lane*16.
__device__ __forceinline__ void g2l16(const void* g, void* l) {
  __builtin_amdgcn_global_load_lds(
      (__attribute__((address_space(1))) void*)g,
      (__attribute__((address_space(3))) void*)l, 16, 0, 0);
}

// ---------------------------------------------------------------------------
// Kernel 1: layernorm (+ latent modulation), f32 -> f16, into concat kv_in
// ---------------------------------------------------------------------------
__global__ __launch_bounds__(256) void ln_mod_kernel(
    const float* __restrict__ x, const float* __restrict__ lat,
    const float* __restrict__ shift, const float* __restrict__ scale,
    const float* __restrict__ ln1w, const float* __restrict__ ln1b,
    const float* __restrict__ ln2w, const float* __restrict__ ln2b,
    f16* __restrict__ kv_in) {
  const int row = blockIdx.x;
  const int b = row / LTOT;
  const int n = row - b * LTOT;
  const int tid = threadIdx.x;
  const bool is_lat = (n >= N1);
  const float* src = is_lat ? (lat + (size_t)(b * N2 + (n - N1)) * DIMD)
                            : (x + (size_t)(b * N1 + n) * DIMD);
  float4 v = ((const float4*)src)[tid];
  float s = v.x + v.y + v.z + v.w;
  float s2 = v.x * v.x + v.y * v.y + v.z * v.z + v.w * v.w;
#pragma unroll
  for (int m = 1; m <= 32; m <<= 1) {
    s += __shfl_xor(s, m, 64);
    s2 += __shfl_xor(s2, m, 64);
  }
  __shared__ float red[8];
  const int wave = tid >> 6;
  if ((tid & 63) == 0) { red[wave * 2] = s; red[wave * 2 + 1] = s2; }
  __syncthreads();
  s = red[0] + red[2] + red[4] + red[6];
  s2 = red[1] + red[3] + red[5] + red[7];
  const float mean = s * (1.0f / DIMD);
  const float var = fmaxf(s2 * (1.0f / DIMD) - mean * mean, 0.0f);
  const float rstd = rsqrtf(var + 1e-5f);
  const float4 w4 = ((const float4*)(is_lat ? ln2w : ln1w))[tid];
  const float4 b4 = ((const float4*)(is_lat ? ln2b : ln1b))[tid];
  float y0 = (v.x - mean) * rstd * w4.x + b4.x;
  float y1 = (v.y - mean) * rstd * w4.y + b4.y;
  float y2 = (v.z - mean) * rstd * w4.z + b4.z;
  float y3 = (v.w - mean) * rstd * w4.w + b4.w;
  if (is_lat) {
    float4 sc = ((const float4*)(scale + (size_t)b * DIMD))[tid];
    float4 sh = ((const float4*)(shift + (size_t)b * DIMD))[tid];
    y0 = y0 * (1.0f + sc.x) + sh.x;
    y1 = y1 * (1.0f + sc.y) + sh.y;
    y2 = y2 * (1.0f + sc.z) + sh.z;
    y3 = y3 * (1.0f + sc.w) + sh.w;
  }
  f16x4_t o = {(f16)y0, (f16)y1, (f16)y2, (f16)y3};
  *(f16x4_t*)(kv_in + (size_t)row * DIMD + tid * 4) = o;
}

// ---------------------------------------------------------------------------
// Kernel 2: f32 -> f16 cast (weights)
// ---------------------------------------------------------------------------
__global__ __launch_bounds__(256) void cast_kernel(const float* __restrict__ in,
                                                   f16* __restrict__ out, int n4) {
  const int i = blockIdx.x * 256 + threadIdx.x;
  if (i < n4) {
    float4 v = ((const float4*)in)[i];
    f16x4_t o = {(f16)v.x, (f16)v.y, (f16)v.z, (f16)v.w};
    ((f16x4_t*)out)[i] = o;
  }
}

// ---------------------------------------------------------------------------
// Kernel 3: 128x128-tile GEMM, C = A (MxK rowmajor f16) * BT (NxK rowmajor f16)
// m97 structure: BK=32, global_load_lds 16B staging, 16x16x32 f16 MFMA.
// MODE 0: kv GEMM -> scatter to k_buf (b,h,n,d) and v_buf transposed (b,h,d,n)
// MODE 1: q GEMM (A rows = latent rows inside kv_in) -> q_buf (b,h,n,d)
// MODE 2: out GEMM -> f32 d_out
// ---------------------------------------------------------------------------
template <int MODE>
__global__ __launch_bounds__(256) void gemm128(
    const f16* __restrict__ A0, const f16* __restrict__ BT,
    void* __restrict__ out0, void* __restrict__ out1) {
  const int mt = blockIdx.x, nt = blockIdx.y;
  const f16* Abase;
  if (MODE == 1) {
    const int bb = mt >> 1;
    Abase = A0 + ((size_t)(bb * LTOT + N1 + (mt & 1) * 128)) * DIMD;
  } else {
    Abase = A0 + (size_t)mt * 128 * DIMD;
  }
  const f16* Bbase = BT + (size_t)nt * 128 * DIMD;
  __shared__ alignas(16) f16 As[128 * 32];
  __shared__ alignas(16) f16 Bs[128 * 32];
  const int tid = threadIdx.x;
  const int wave = tid >> 6, lane = tid & 63;
  const int wm = (wave & 1) * 64, wn = (wave >> 1) * 64;
  const int lrow = lane >> 2, lcol = (lane & 3) * 8;
  const int r16 = lane & 15, g8 = (lane >> 4) * 8, q4 = (lane >> 4) * 4;
  f32x4_t acc[4][4] = {};
  for (int k0 = 0; k0 < DIMD; k0 += 32) {
    __syncthreads();
    g2l16(Abase + (size_t)(wave * 16 + lrow) * DIMD + k0 + lcol, &As[(wave * 16) * 32]);
    g2l16(Abase + (size_t)(64 + wave * 16 + lrow) * DIMD + k0 + lcol, &As[(64 + wave * 16) * 32]);
    g2l16(Bbase + (size_t)(wave * 16 + lrow) * DIMD + k0 + lcol, &Bs[(wave * 16) * 32]);
    g2l16(Bbase + (size_t)(64 + wave * 16 + lrow) * DIMD + k0 + lcol, &Bs[(64 + wave * 16) * 32]);
    __syncthreads();
    f16x8_t a[4], bf[4];
#pragma unroll
    for (int i = 0; i < 4; i++)
      a[i] = *(const f16x8_t*)&As[(wm + i * 16 + r16) * 32 + g8];
#pragma unroll
    for (int j = 0; j < 4; j++)
      bf[j] = *(const f16x8_t*)&Bs[(wn + j * 16 + r16) * 32 + g8];
#pragma unroll
    for (int i = 0; i < 4; i++)
#pragma unroll
      for (int j = 0; j < 4; j++)
        acc[i][j] = __builtin_amdgcn_mfma_f32_16x16x32_f16(a[i], bf[j], acc[i][j], 0, 0, 0);
  }

  if constexpr (MODE == 0) {
    const int m0 = mt * 128;
    const int b = m0 / LTOT;
    const int n0 = m0 - b * LTOT;
    const int e0 = nt * 128;
    if (e0 < 1024) {  // k half: layout ((b*16+h)*4352 + n)*64 + d
      f16* kbuf = (f16*)out0;
#pragma unroll
      for (int i = 0; i < 4; i++) {
        const int n_base = n0 + wm + i * 16 + q4;
#pragma unroll
        for (int j = 0; j < 4; j++) {
          const int e = e0 + wn + j * 16 + r16;
          const int h = e >> 6, d = e & 63;
          const size_t base = ((size_t)(b * HEADS + h) * LTOT);
#pragma unroll
          for (int r = 0; r < 4; r++)
            kbuf[(base + n_base + r) * DH + d] = (f16)acc[i][j][r];
        }
      }
    } else {  // v half, transposed: ((b*16+h)*64 + d)*4352 + n
      f16* vbuf = (f16*)out1;
      const int e0v = e0 - 1024;
#pragma unroll
      for (int i = 0; i < 4; i++) {
        const int n_base = n0 + wm + i * 16 + q4;
#pragma unroll
        for (int j = 0; j < 4; j++) {
          const int e = e0v + wn + j * 16 + r16;
          const int h = e >> 6, d = e & 63;
          f16x4_t pk = {(f16)acc[i][j][0], (f16)acc[i][j][1],
                        (f16)acc[i][j][2], (f16)acc[i][j][3]};
          *(f16x4_t*)&vbuf[((size_t)(b * HEADS + h) * DH + d) * LTOT + n_base] = pk;
        }
      }
    }
  } else if constexpr (MODE == 1) {  // q: ((b*16+h)*256 + n)*64 + d
    f16* qbuf = (f16*)out0;
    const int b = mt >> 1;
#pragma unroll
    for (int i = 0; i < 4; i++) {
      const int n_base = (mt & 1) * 128 + wm + i * 16 + q4;
#pragma unroll
      for (int j = 0; j < 4; j++) {
        const int e = nt * 128 + wn + j * 16 + r16;
        const int h = e >> 6, d = e & 63;
#pragma unroll
        for (int r = 0; r < 4; r++)
          qbuf[((size_t)(b * HEADS + h) * N2 + n_base + r) * DH + d] = (f16)acc[i][j][r];
      }
    }
  } else {  // final output, f32
    float* outp = (float*)out0;
    const int m0 = mt * 128;
#pragma unroll
    for (int i = 0; i < 4; i++) {
#pragma unroll
      for (int j = 0; j < 4; j++) {
        const int col = nt * 128 + wn + j * 16 + r16;
#pragma unroll
        for (int r = 0; r < 4; r++)
          outp[(size_t)(m0 + wm + i * 16 + q4 + r) * DIMD + col] = acc[i][j][r];
      }
    }
  }
}

// ---------------------------------------------------------------------------
// Kernel 4: flash attention, transposed compute, split-K (flash-decode).
//   S^T = K * Q^T    (A = K tile rowmajor, B^T = Q rowmajor)
//   O^T = Vt * P^T   (A = Vt tile rowmajor, B^T = P rowmajor)
// blockIdx.x = ((bh*2 + qt)*2 + ks); each block does 17 of the 34 k-tiles and
// writes unnormalized O (f32) + (m,l) partials. 512 blocks -> 2 blocks/CU so
// barrier/staging stalls overlap across resident blocks (m114).
// ---------------------------------------------------------------------------
__global__ __launch_bounds__(256, 1) void attn_kernel(
    const f16* __restrict__ qbuf, const f16* __restrict__ kbuf,
    const f16* __restrict__ vbuf, float* __restrict__ Op,
    float* __restrict__ ml) {
  const int part = blockIdx.x;
  const int bh = part >> 2;
  const int qt = (part >> 1) & 1;
  const int ks = part & 1;
  const f16* qg = qbuf + ((size_t)bh * N2 + qt * 128) * DH;
  const f16* kg = kbuf + (size_t)bh * LTOT * DH;
  const f16* vg = vbuf + (size_t)bh * DH * LTOT;

  __shared__ alignas(16) f16 Rh[17408];       // 34816 B (K|Q, later P)
  __shared__ alignas(16) f16 Vs[4][64 * 32];  // 16384 B, Vt in 4 key-chunks

  const int tid = threadIdx.x, wave = tid >> 6, lane = tid & 63;
  const int lrow = lane >> 2, lcol = (lane & 3) * 8;
  const int r16 = lane & 15, g8 = (lane >> 4) * 8, q4 = (lane >> 4) * 4;
  f16* Ps = &Rh[wave * 4352];  // 32 rows x 136 halves, per-wave private

  // stage Q once into Rh[8192..), then hold fragments in registers
#pragma unroll
  for (int s = 0; s < 2; s++)
#pragma unroll
    for (int half = 0; half < 2; half++) {
      const int r0 = half * 64 + wave * 16;
      g2l16(qg + (size_t)(r0 + lrow) * DH + s * 32 + lcol,
            &Rh[8192 + s * 4096 + r0 * 32]);
    }
  __syncthreads();
  f16x8_t bQ[2][2];
#pragma unroll
  for (int s = 0; s < 2; s++)
#pragma unroll
    for (int j = 0; j < 2; j++)
      bQ[s][j] = *(const f16x8_t*)&Rh[8192 + s * 4096 + (wave * 32 + j * 16 + r16) * 32 + g8];

  f32x4_t oacc[4][2] = {};
  float mrow[2] = {-1e30f, -1e30f};
  float lsum[2] = {0.0f, 0.0f};
  const float SCL = 0.125f * 1.44269504089f;  // fold attn_scale^2 and log2(e)

  for (int kt = ks * KT_PER; kt < ks * KT_PER + KT_PER; kt++) {
    __syncthreads();  // prior-iteration LDS reads drained
    // stage K tile (2 d-halves) into Rh[0..8192)
#pragma unroll
    for (int s = 0; s < 2; s++)
#pragma unroll
      for (int half = 0; half < 2; half++) {
        const int r0 = half * 64 + wave * 16;
        g2l16(kg + (size_t)(kt * 128 + r0 + lrow) * DH + s * 32 + lcol,
              &Rh[s * 4096 + r0 * 32]);
      }
    // stage Vt key-chunk (wave w handles chunk w)
#pragma unroll
    for (int dg = 0; dg < 4; dg++) {
      const int d0 = dg * 16;
      g2l16(vg + (size_t)(d0 + lrow) * LTOT + kt * 128 + wave * 32 + lcol,
            &Vs[wave][d0 * 32]);
    }
    __syncthreads();
    // S^T = K * Q^T
    f32x4_t sacc[8][2] = {};
#pragma unroll
    for (int s = 0; s < 2; s++) {
      f16x8_t aK[8];
#pragma unroll
      for (int i = 0; i < 8; i++)
        aK[i] = *(const f16x8_t*)&Rh[s * 4096 + (i * 16 + r16) * 32 + g8];
#pragma unroll
      for (int i = 0; i < 8; i++)
#pragma unroll
        for (int j = 0; j < 2; j++)
          sacc[i][j] = __builtin_amdgcn_mfma_f32_16x16x32_f16(aK[i], bQ[s][j], sacc[i][j], 0, 0, 0);
    }
    __syncthreads();  // all waves done reading K before P overlays Rh
    // online softmax, base-2 domain; per-lane qcol = j*16 + (lane&15)
#pragma unroll
    for (int j = 0; j < 2; j++) {
      float vmax = -1e30f;
#pragma unroll
      for (int i = 0; i < 8; i++)
#pragma unroll
        for (int r = 0; r < 4; r++) vmax = fmaxf(vmax, sacc[i][j][r]);
      vmax = fmaxf(vmax, __shfl_xor(vmax, 16, 64));
      vmax = fmaxf(vmax, __shfl_xor(vmax, 32, 64));
      const float m_new = fmaxf(mrow[j], SCL * vmax);
      const float alpha = exp2f(mrow[j] - m_new);
      float psum = 0.0f;
#pragma unroll
      for (int i = 0; i < 8; i++) {
        f16x4_t pk;
#pragma unroll
        for (int r = 0; r < 4; r++) {
          const float p = exp2f(SCL * sacc[i][j][r] - m_new);
          psum += p;
          pk[r] = (f16)p;
        }
        *(f16x4_t*)&Ps[(j * 16 + r16) * 136 + i * 16 + q4] = pk;  // key consec in r
      }
      psum += __shfl_xor(psum, 16, 64);
      psum += __shfl_xor(psum, 32, 64);
      lsum[j] = lsum[j] * alpha + psum;
      mrow[j] = m_new;
#pragma unroll
      for (int id = 0; id < 4; id++) oacc[id][j] *= alpha;
    }
    // O^T += Vt * P^T  (per-wave private P, DS ops in-order -> no barrier)
#pragma unroll
    for (int s2 = 0; s2 < 4; s2++) {
      f16x8_t aV[4];
#pragma unroll
      for (int id = 0; id < 4; id++)
        aV[id] = *(const f16x8_t*)&Vs[s2][(id * 16 + r16) * 32 + g8];
      f16x8_t bP[2];
#pragma unroll
      for (int j = 0; j < 2; j++)
        bP[j] = *(const f16x8_t*)&Ps[(j * 16 + r16) * 136 + s2 * 32 + g8];
#pragma unroll
      for (int id = 0; id < 4; id++)
#pragma unroll
        for (int j = 0; j < 2; j++)
          oacc[id][j] = __builtin_amdgcn_mfma_f32_16x16x32_f16(aV[id], bP[j], oacc[id][j], 0, 0, 0);
    }
  }
  // epilogue: write unnormalized partials.
  // O^T C-layout: d = id*16 + q4 + r (r = float4 lane), q = wave*32 + j*16 + r16
  float* Opb = Op + (size_t)part * 128 * 64;
#pragma unroll
  for (int j = 0; j < 2; j++) {
    const int q_local = wave * 32 + j * 16 + r16;
#pragma unroll
    for (int id = 0; id < 4; id++)
      *(float4*)&Opb[(size_t)q_local * 64 + id * 16 + q4] = *(float4*)&oacc[id][j];
    if (lane < 16) {
      const size_t mi = ((size_t)part * 128 + wave * 32 + j * 16 + lane) * 2;
      ml[mi] = mrow[j];
      ml[mi + 1] = lsum[j];
    }
  }
}

// ---------------------------------------------------------------------------
// Kernel 5: merge split-K partials -> f16 attn_out rowmajor (b*256+q, 1024)
// ---------------------------------------------------------------------------
__global__ __launch_bounds__(256) void attn_merge_kernel(
    const float* __restrict__ Op, const float* __restrict__ ml,
    f16* __restrict__ aout) {
  const int bq = blockIdx.x;  // bh*2 + qt
  const int bh = bq >> 1, qt = bq & 1;
  const int b = bh >> 4, h = bh & 15;
  const int tid = threadIdx.x;
  __shared__ float w0s[128], w1s[128];
  if (tid < 128) {
    const size_t i0 = ((size_t)(bq * 2 + 0) * 128 + tid) * 2;
    const size_t i1 = ((size_t)(bq * 2 + 1) * 128 + tid) * 2;
    const float m0 = ml[i0], l0 = ml[i0 + 1];
    const float m1 = ml[i1], l1 = ml[i1 + 1];
    const float M = fmaxf(m0, m1);
    const float w0 = exp2f(m0 - M), w1 = exp2f(m1 - M);
    const float invL = 1.0f / (l0 * w0 + l1 * w1);
    w0s[tid] = w0 * invL;
    w1s[tid] = w1 * invL;
  }
  __syncthreads();
  const float4* O0 = (const float4*)(Op + (size_t)(bq * 2 + 0) * 128 * 64);
  const float4* O1 = (const float4*)(Op + (size_t)(bq * 2 + 1) * 128 * 64);
#pragma unroll
  for (int p = 0; p < 8; p++) {
    const int idx = p * 256 + tid;  // over 128 q x 16 float4-cols
    const int q = idx >> 4, c = idx & 15;
    const float4 a = O0[idx], bb = O1[idx];
    const float w0 = w0s[q], w1 = w1s[q];
    f16x4_t o = {(f16)(a.x * w0 + bb.x * w1), (f16)(a.y * w0 + bb.y * w1),
                 (f16)(a.z * w0 + bb.z * w1), (f16)(a.w * w0 + bb.w * w1)};
    *(f16x4_t*)&aout[((size_t)(b * N2 + qt * 128 + q)) * DIMD + h * DH + c * 4] = o;
  }
}

// ---------------------------------------------------------------------------
extern "C" void kernel_launch(void* const* d_in, const int* in_sizes, int n_in,
                              void* d_out, int out_size, void* d_ws, size_t ws_size,
                              hipStream_t stream) {
  const float* x     = (const float*)d_in[0];
  const float* lat   = (const float*)d_in[1];
  const float* shift = (const float*)d_in[2];
  const float* scale = (const float*)d_in[3];
  const float* ln1w  = (const float*)d_in[4];
  const float* ln1b  = (const float*)d_in[5];
  const float* ln2w  = (const float*)d_in[6];
  const float* ln2b  = (const float*)d_in[7];
  const float* Wq    = (const float*)d_in[8];
  const float* Wkv   = (const float*)d_in[9];
  const float* Wo    = (const float*)d_in[10];
  float* outp = (float*)d_out;

  char* ws = (char*)d_ws;
  f16* kv_in = (f16*)ws;                 ws += (size_t)MKV * DIMD * 2;          // 68 MB
  f16* Wq16  = (f16*)ws;                 ws += (size_t)1024 * 1024 * 2;         // 2 MB
  f16* Wkv16 = (f16*)ws;                 ws += (size_t)2048 * 1024 * 2;         // 4 MB
  f16* Wo16  = (f16*)ws;                 ws += (size_t)1024 * 1024 * 2;         // 2 MB
  f16* qbuf  = (f16*)ws;                 ws += (size_t)B_SZ * HEADS * N2 * DH * 2;   // 4 MB
  f16* kbuf  = (f16*)ws;                 ws += (size_t)B_SZ * HEADS * LTOT * DH * 2; // 68 MB
  f16* vbuf  = (f16*)ws;                 ws += (size_t)B_SZ * HEADS * LTOT * DH * 2; // 68 MB
  f16* aout  = (f16*)ws;                 ws += (size_t)B_SZ * N2 * DIMD * 2;         // 4 MB

  // split-K partials alias the kv_in region: kv_in is dead after the q-GEMM,
  // which runs before attn in-stream. Opart 16.78 MB + ml 0.13 MB << 68 MB.
  float* Opart = (float*)kv_in;                                   // 512*128*64 f32
  float* mlbuf = (float*)(kv_in + (size_t)512 * 128 * 64 * 2);    // 512*128*2 f32

  ln_mod_kernel<<<dim3(MKV), dim3(256), 0, stream>>>(x, lat, shift, scale, ln1w,
                                                     ln1b, ln2w, ln2b, kv_in);
  cast_kernel<<<dim3(1024), dim3(256), 0, stream>>>(Wq, Wq16, 1024 * 1024 / 4);
  cast_kernel<<<dim3(2048), dim3(256), 0, stream>>>(Wkv, Wkv16, 2048 * 1024 / 4);
  cast_kernel<<<dim3(1024), dim3(256), 0, stream>>>(Wo, Wo16, 1024 * 1024 / 4);

  gemm128<0><<<dim3(MKV / 128, 16), dim3(256), 0, stream>>>(kv_in, Wkv16, kbuf, vbuf);
  gemm128<1><<<dim3(16, 8), dim3(256), 0, stream>>>(kv_in, Wq16, qbuf, nullptr);
  attn_kernel<<<dim3(128 * 2 * KSPLIT), dim3(256), 0, stream>>>(qbuf, kbuf, vbuf,
                                                                Opart, mlbuf);
  attn_merge_kernel<<<dim3(256), dim3(256), 0, stream>>>(Opart, mlbuf, aout);
  gemm128<2><<<dim3(16, 8), dim3(256), 0, stream>>>(aout, Wo16, outp, nullptr);
}

// Round 4
// 606.630 us; speedup vs baseline: 1.0088x; 1.0088x over previous
//
#include <hip/hip_runtime.h>
#include <cstdint>
#include <cstddef>

#define B_SZ 8
#define N1 4096
#define N2 256
#define LTOT 4352          // N1 + N2
#define DIMD 1024
#define HEADS 16
#define DH 64
#define MKV (B_SZ * LTOT)  // 34816

typedef _Float16 f16;
typedef f16 f16x4_t __attribute__((ext_vector_type(4)));
typedef f16 f16x8_t __attribute__((ext_vector_type(8)));
typedef float f32x4_t __attribute__((ext_vector_type(4)));

// async global -> LDS, 16B per lane. LDS dest is wave-uniform base + lane*16.
__device__ __forceinline__ void g2l16(const void* g, void* l) {
  __builtin_amdgcn_global_load_lds(
      (__attribute__((address_space(1))) void*)g,
      (__attribute__((address_space(3))) void*)l, 16, 0, 0);
}

// ---------------------------------------------------------------------------
// Kernel 1: layernorm (+ latent modulation), f32 -> f16, into concat kv_in
// ---------------------------------------------------------------------------
__global__ __launch_bounds__(256) void ln_mod_kernel(
    const float* __restrict__ x, const float* __restrict__ lat,
    const float* __restrict__ shift, const float* __restrict__ scale,
    const float* __restrict__ ln1w, const float* __restrict__ ln1b,
    const float* __restrict__ ln2w, const float* __restrict__ ln2b,
    f16* __restrict__ kv_in) {
  const int row = blockIdx.x;
  const int b = row / LTOT;
  const int n = row - b * LTOT;
  const int tid = threadIdx.x;
  const bool is_lat = (n >= N1);
  const float* src = is_lat ? (lat + (size_t)(b * N2 + (n - N1)) * DIMD)
                            : (x + (size_t)(b * N1 + n) * DIMD);
  float4 v = ((const float4*)src)[tid];
  float s = v.x + v.y + v.z + v.w;
  float s2 = v.x * v.x + v.y * v.y + v.z * v.z + v.w * v.w;
#pragma unroll
  for (int m = 1; m <= 32; m <<= 1) {
    s += __shfl_xor(s, m, 64);
    s2 += __shfl_xor(s2, m, 64);
  }
  __shared__ float red[8];
  const int wave = tid >> 6;
  if ((tid & 63) == 0) { red[wave * 2] = s; red[wave * 2 + 1] = s2; }
  __syncthreads();
  s = red[0] + red[2] + red[4] + red[6];
  s2 = red[1] + red[3] + red[5] + red[7];
  const float mean = s * (1.0f / DIMD);
  const float var = fmaxf(s2 * (1.0f / DIMD) - mean * mean, 0.0f);
  const float rstd = rsqrtf(var + 1e-5f);
  const float4 w4 = ((const float4*)(is_lat ? ln2w : ln1w))[tid];
  const float4 b4 = ((const float4*)(is_lat ? ln2b : ln1b))[tid];
  float y0 = (v.x - mean) * rstd * w4.x + b4.x;
  float y1 = (v.y - mean) * rstd * w4.y + b4.y;
  float y2 = (v.z - mean) * rstd * w4.z + b4.z;
  float y3 = (v.w - mean) * rstd * w4.w + b4.w;
  if (is_lat) {
    float4 sc = ((const float4*)(scale + (size_t)b * DIMD))[tid];
    float4 sh = ((const float4*)(shift + (size_t)b * DIMD))[tid];
    y0 = y0 * (1.0f + sc.x) + sh.x;
    y1 = y1 * (1.0f + sc.y) + sh.y;
    y2 = y2 * (1.0f + sc.z) + sh.z;
    y3 = y3 * (1.0f + sc.w) + sh.w;
  }
  f16x4_t o = {(f16)y0, (f16)y1, (f16)y2, (f16)y3};
  *(f16x4_t*)(kv_in + (size_t)row * DIMD + tid * 4) = o;
}

// ---------------------------------------------------------------------------
// Kernel 2: f32 -> f16 cast (weights)
// ---------------------------------------------------------------------------
__global__ __launch_bounds__(256) void cast_kernel(const float* __restrict__ in,
                                                   f16* __restrict__ out, int n4) {
  const int i = blockIdx.x * 256 + threadIdx.x;
  if (i < n4) {
    float4 v = ((const float4*)in)[i];
    f16x4_t o = {(f16)v.x, (f16)v.y, (f16)v.z, (f16)v.w};
    ((f16x4_t*)out)[i] = o;
  }
}

// ---------------------------------------------------------------------------
// Kernel 3: 128x128-tile GEMM, C = A (MxK rowmajor f16) * BT (NxK rowmajor f16)
// m97 structure: BK=32, global_load_lds 16B staging, 16x16x32 f16 MFMA.
// Grid is (nt_count, mt_count) with nt FASTEST: the ~256 co-resident blocks
// cover 32 mt x 8 nt (10 MB working set) so each A-tile is consumed by all
// its nt-blocks within one residency round -> A fetched from HBM once and
// staging drains hit L2/L3 instead of HBM.
// MODE 0: kv GEMM -> scatter to k_buf (b,h,n,d) / v_buf transposed (b,h,d,n)
// MODE 1: q GEMM (A rows = latent rows inside kv_in) -> q_buf (b,h,n,d)
// MODE 2: out GEMM -> f32 d_out
// ---------------------------------------------------------------------------
template <int MODE>
__global__ __launch_bounds__(256) void gemm128(
    const f16* __restrict__ A0, const f16* __restrict__ BT,
    void* __restrict__ out0, void* __restrict__ out1, int nt_base) {
  const int mt = blockIdx.y, nt = nt_base + blockIdx.x;
  const f16* Abase;
  if (MODE == 1) {
    const int bb = mt >> 1;
    Abase = A0 + ((size_t)(bb * LTOT + N1 + (mt & 1) * 128)) * DIMD;
  } else {
    Abase = A0 + (size_t)mt * 128 * DIMD;
  }
  const f16* Bbase = BT + (size_t)nt * 128 * DIMD;
  __shared__ alignas(16) f16 As[128 * 32];
  __shared__ alignas(16) f16 Bs[128 * 32];
  const int tid = threadIdx.x;
  const int wave = tid >> 6, lane = tid & 63;
  const int wm = (wave & 1) * 64, wn = (wave >> 1) * 64;
  const int lrow = lane >> 2, lcol = (lane & 3) * 8;
  const int r16 = lane & 15, g8 = (lane >> 4) * 8, q4 = (lane >> 4) * 4;
  f32x4_t acc[4][4] = {};
  for (int k0 = 0; k0 < DIMD; k0 += 32) {
    __syncthreads();
    g2l16(Abase + (size_t)(wave * 16 + lrow) * DIMD + k0 + lcol, &As[(wave * 16) * 32]);
    g2l16(Abase + (size_t)(64 + wave * 16 + lrow) * DIMD + k0 + lcol, &As[(64 + wave * 16) * 32]);
    g2l16(Bbase + (size_t)(wave * 16 + lrow) * DIMD + k0 + lcol, &Bs[(wave * 16) * 32]);
    g2l16(Bbase + (size_t)(64 + wave * 16 + lrow) * DIMD + k0 + lcol, &Bs[(64 + wave * 16) * 32]);
    __syncthreads();
    f16x8_t a[4], bf[4];
#pragma unroll
    for (int i = 0; i < 4; i++)
      a[i] = *(const f16x8_t*)&As[(wm + i * 16 + r16) * 32 + g8];
#pragma unroll
    for (int j = 0; j < 4; j++)
      bf[j] = *(const f16x8_t*)&Bs[(wn + j * 16 + r16) * 32 + g8];
#pragma unroll
    for (int i = 0; i < 4; i++)
#pragma unroll
      for (int j = 0; j < 4; j++)
        acc[i][j] = __builtin_amdgcn_mfma_f32_16x16x32_f16(a[i], bf[j], acc[i][j], 0, 0, 0);
  }

  if constexpr (MODE == 0) {
    const int m0 = mt * 128;
    const int b = m0 / LTOT;
    const int n0 = m0 - b * LTOT;
    const int e0 = nt * 128;
    if (e0 < 1024) {  // k half: layout ((b*16+h)*4352 + n)*64 + d
      f16* kbuf = (f16*)out0;
#pragma unroll
      for (int i = 0; i < 4; i++) {
        const int n_base = n0 + wm + i * 16 + q4;
#pragma unroll
        for (int j = 0; j < 4; j++) {
          const int e = e0 + wn + j * 16 + r16;
          const int h = e >> 6, d = e & 63;
          const size_t base = ((size_t)(b * HEADS + h) * LTOT);
#pragma unroll
          for (int r = 0; r < 4; r++)
            kbuf[(base + n_base + r) * DH + d] = (f16)acc[i][j][r];
        }
      }
    } else {  // v half, transposed: ((b*16+h)*64 + d)*4352 + n
      f16* vbuf = (f16*)out1;
      const int e0v = e0 - 1024;
#pragma unroll
      for (int i = 0; i < 4; i++) {
        const int n_base = n0 + wm + i * 16 + q4;
#pragma unroll
        for (int j = 0; j < 4; j++) {
          const int e = e0v + wn + j * 16 + r16;
          const int h = e >> 6, d = e & 63;
          f16x4_t pk = {(f16)acc[i][j][0], (f16)acc[i][j][1],
                        (f16)acc[i][j][2], (f16)acc[i][j][3]};
          *(f16x4_t*)&vbuf[((size_t)(b * HEADS + h) * DH + d) * LTOT + n_base] = pk;
        }
      }
    }
  } else if constexpr (MODE == 1) {  // q: ((b*16+h)*256 + n)*64 + d
    f16* qbuf = (f16*)out0;
    const int b = mt >> 1;
#pragma unroll
    for (int i = 0; i < 4; i++) {
      const int n_base = (mt & 1) * 128 + wm + i * 16 + q4;
#pragma unroll
      for (int j = 0; j < 4; j++) {
        const int e = nt * 128 + wn + j * 16 + r16;
        const int h = e >> 6, d = e & 63;
#pragma unroll
        for (int r = 0; r < 4; r++)
          qbuf[((size_t)(b * HEADS + h) * N2 + n_base + r) * DH + d] = (f16)acc[i][j][r];
      }
    }
  } else {  // final output, f32
    float* outp = (float*)out0;
    const int m0 = mt * 128;
#pragma unroll
    for (int i = 0; i < 4; i++) {
#pragma unroll
      for (int j = 0; j < 4; j++) {
        const int col = nt * 128 + wn + j * 16 + r16;
#pragma unroll
        for (int r = 0; r < 4; r++)
          outp[(size_t)(m0 + wm + i * 16 + q4 + r) * DIMD + col] = acc[i][j][r];
      }
    }
  }
}

// ---------------------------------------------------------------------------
// Kernel 4: flash attention, transposed compute (R1 structure, no split-K).
//   S^T = K * Q^T    (A = K tile rowmajor, B^T = Q rowmajor)
//   O^T = Vt * P^T   (A = Vt tile rowmajor, B^T = P rowmajor)
// Each wave owns 32 q-columns; softmax stats wave-local (shfl over hi lanes).
// LDS aliasing: Rh = [K tile 16KB | Q tile 16KB(+)], P (34816B) overlays Rh.
// ---------------------------------------------------------------------------
__global__ __launch_bounds__(256, 1) void attn_kernel(
    const f16* __restrict__ qbuf, const f16* __restrict__ kbuf,
    const f16* __restrict__ vbuf, f16* __restrict__ attn_out) {
  const int bh = blockIdx.x >> 1;
  const int qt = blockIdx.x & 1;
  const int b = bh >> 4, h = bh & 15;
  const f16* qg = qbuf + ((size_t)bh * N2 + qt * 128) * DH;
  const f16* kg = kbuf + (size_t)bh * LTOT * DH;
  const f16* vg = vbuf + (size_t)bh * DH * LTOT;

  __shared__ alignas(16) f16 Rh[17408];       // 34816 B (K|Q, later P)
  __shared__ alignas(16) f16 Vs[4][64 * 32];  // 16384 B, Vt in 4 key-chunks

  const int tid = threadIdx.x, wave = tid >> 6, lane = tid & 63;
  const int lrow = lane >> 2, lcol = (lane & 3) * 8;
  const int r16 = lane & 15, g8 = (lane >> 4) * 8, q4 = (lane >> 4) * 4;
  f16* Ps = &Rh[wave * 4352];  // 32 rows x 136 halves, per-wave private

  // stage Q once into Rh[8192..), then hold fragments in registers
#pragma unroll
  for (int s = 0; s < 2; s++)
#pragma unroll
    for (int half = 0; half < 2; half++) {
      const int r0 = half * 64 + wave * 16;
      g2l16(qg + (size_t)(r0 + lrow) * DH + s * 32 + lcol,
            &Rh[8192 + s * 4096 + r0 * 32]);
    }
  __syncthreads();
  f16x8_t bQ[2][2];
#pragma unroll
  for (int s = 0; s < 2; s++)
#pragma unroll
    for (int j = 0; j < 2; j++)
      bQ[s][j] = *(const f16x8_t*)&Rh[8192 + s * 4096 + (wave * 32 + j * 16 + r16) * 32 + g8];

  f32x4_t oacc[4][2] = {};
  float mrow[2] = {-1e30f, -1e30f};
  float lsum[2] = {0.0f, 0.0f};
  const float SCL = 0.125f * 1.44269504089f;  // fold attn_scale^2 and log2(e)

  for (int kt = 0; kt < LTOT / 128; kt++) {
    __syncthreads();  // prior-iteration LDS reads drained
    // stage K tile (2 d-halves) into Rh[0..8192)
#pragma unroll
    for (int s = 0; s < 2; s++)
#pragma unroll
      for (int half = 0; half < 2; half++) {
        const int r0 = half * 64 + wave * 16;
        g2l16(kg + (size_t)(kt * 128 + r0 + lrow) * DH + s * 32 + lcol,
              &Rh[s * 4096 + r0 * 32]);
      }
    // stage Vt key-chunk (wave w handles chunk w)
#pragma unroll
    for (int dg = 0; dg < 4; dg++) {
      const int d0 = dg * 16;
      g2l16(vg + (size_t)(d0 + lrow) * LTOT + kt * 128 + wave * 32 + lcol,
            &Vs[wave][d0 * 32]);
    }
    __syncthreads();
    // S^T = K * Q^T
    f32x4_t sacc[8][2] = {};
#pragma unroll
    for (int s = 0; s < 2; s++) {
      f16x8_t aK[8];
#pragma unroll
      for (int i = 0; i < 8; i++)
        aK[i] = *(const f16x8_t*)&Rh[s * 4096 + (i * 16 + r16) * 32 + g8];
#pragma unroll
      for (int i = 0; i < 8; i++)
#pragma unroll
        for (int j = 0; j < 2; j++)
          sacc[i][j] = __builtin_amdgcn_mfma_f32_16x16x32_f16(aK[i], bQ[s][j], sacc[i][j], 0, 0, 0);
    }
    __syncthreads();  // all waves done reading K before P overlays Rh
    // online softmax, base-2 domain; per-lane qcol = j*16 + (lane&15)
#pragma unroll
    for (int j = 0; j < 2; j++) {
      float vmax = -1e30f;
#pragma unroll
      for (int i = 0; i < 8; i++)
#pragma unroll
        for (int r = 0; r < 4; r++) vmax = fmaxf(vmax, sacc[i][j][r]);
      vmax = fmaxf(vmax, __shfl_xor(vmax, 16, 64));
      vmax = fmaxf(vmax, __shfl_xor(vmax, 32, 64));
      const float m_new = fmaxf(mrow[j], SCL * vmax);
      const float alpha = exp2f(mrow[j] - m_new);
      float psum = 0.0f;
#pragma unroll
      for (int i = 0; i < 8; i++) {
        f16x4_t pk;
#pragma unroll
        for (int r = 0; r < 4; r++) {
          const float p = exp2f(SCL * sacc[i][j][r] - m_new);
          psum += p;
          pk[r] = (f16)p;
        }
        *(f16x4_t*)&Ps[(j * 16 + r16) * 136 + i * 16 + q4] = pk;  // key consec in r
      }
      psum += __shfl_xor(psum, 16, 64);
      psum += __shfl_xor(psum, 32, 64);
      lsum[j] = lsum[j] * alpha + psum;
      mrow[j] = m_new;
#pragma unroll
      for (int id = 0; id < 4; id++) oacc[id][j] *= alpha;
    }
    // O^T += Vt * P^T  (per-wave private P, DS ops in-order -> no barrier)
#pragma unroll
    for (int s2 = 0; s2 < 4; s2++) {
      f16x8_t aV[4];
#pragma unroll
      for (int id = 0; id < 4; id++)
        aV[id] = *(const f16x8_t*)&Vs[s2][(id * 16 + r16) * 32 + g8];
      f16x8_t bP[2];
#pragma unroll
      for (int j = 0; j < 2; j++)
        bP[j] = *(const f16x8_t*)&Ps[(j * 16 + r16) * 136 + s2 * 32 + g8];
#pragma unroll
      for (int id = 0; id < 4; id++)
#pragma unroll
        for (int j = 0; j < 2; j++)
          oacc[id][j] = __builtin_amdgcn_mfma_f32_16x16x32_f16(aV[id], bP[j], oacc[id][j], 0, 0, 0);
    }
  }
  // epilogue: attn_out[(b*256+qrow)*1024 + h*64 + d], f16 rowmajor for out-GEMM
#pragma unroll
  for (int j = 0; j < 2; j++) {
    const float inv = 1.0f / lsum[j];
    const int qrow = qt * 128 + wave * 32 + j * 16 + r16;
    const size_t rowbase = ((size_t)(b * N2 + qrow)) * DIMD + h * DH;
#pragma unroll
    for (int id = 0; id < 4; id++) {
      f16x4_t pk;
#pragma unroll
      for (int r = 0; r < 4; r++) pk[r] = (f16)(oacc[id][j][r] * inv);
      *(f16x4_t*)&attn_out[rowbase + id * 16 + q4] = pk;
    }
  }
}

// ---------------------------------------------------------------------------
extern "C" void kernel_launch(void* const* d_in, const int* in_sizes, int n_in,
                              void* d_out, int out_size, void* d_ws, size_t ws_size,
                              hipStream_t stream) {
  const float* x     = (const float*)d_in[0];
  const float* lat   = (const float*)d_in[1];
  const float* shift = (const float*)d_in[2];
  const float* scale = (const float*)d_in[3];
  const float* ln1w  = (const float*)d_in[4];
  const float* ln1b  = (const float*)d_in[5];
  const float* ln2w  = (const float*)d_in[6];
  const float* ln2b  = (const float*)d_in[7];
  const float* Wq    = (const float*)d_in[8];
  const float* Wkv   = (const float*)d_in[9];
  const float* Wo    = (const float*)d_in[10];
  float* outp = (float*)d_out;

  char* ws = (char*)d_ws;
  f16* kv_in = (f16*)ws;                 ws += (size_t)MKV * DIMD * 2;          // 68 MB
  f16* Wq16  = (f16*)ws;                 ws += (size_t)1024 * 1024 * 2;         // 2 MB
  f16* Wkv16 = (f16*)ws;                 ws += (size_t)2048 * 1024 * 2;         // 4 MB
  f16* Wo16  = (f16*)ws;                 ws += (size_t)1024 * 1024 * 2;         // 2 MB
  f16* qbuf  = (f16*)ws;                 ws += (size_t)B_SZ * HEADS * N2 * DH * 2;   // 4 MB
  f16* kbuf  = (f16*)ws;                 ws += (size_t)B_SZ * HEADS * LTOT * DH * 2; // 68 MB
  f16* vbuf  = (f16*)ws;                 ws += (size_t)B_SZ * HEADS * LTOT * DH * 2; // 68 MB
  f16* aout  = (f16*)ws;                 ws += (size_t)B_SZ * N2 * DIMD * 2;         // 4 MB

  ln_mod_kernel<<<dim3(MKV), dim3(256), 0, stream>>>(x, lat, shift, scale, ln1w,
                                                     ln1b, ln2w, ln2b, kv_in);
  cast_kernel<<<dim3(1024), dim3(256), 0, stream>>>(Wq, Wq16, 1024 * 1024 / 4);
  cast_kernel<<<dim3(2048), dim3(256), 0, stream>>>(Wkv, Wkv16, 2048 * 1024 / 4);
  cast_kernel<<<dim3(1024), dim3(256), 0, stream>>>(Wo, Wo16, 1024 * 1024 / 4);

  // kv GEMM split into k-half / v-half dispatches (nt 0-7 and 8-15):
  // same total work, halves the top-5 visibility floor for diagnosis.
  gemm128<0><<<dim3(8, MKV / 128), dim3(256), 0, stream>>>(kv_in, Wkv16, kbuf, vbuf, 0);
  gemm128<0><<<dim3(8, MKV / 128), dim3(256), 0, stream>>>(kv_in, Wkv16, kbuf, vbuf, 8);
  gemm128<1><<<dim3(8, 16), dim3(256), 0, stream>>>(kv_in, Wq16, qbuf, nullptr, 0);
  attn_kernel<<<dim3(256), dim3(256), 0, stream>>>(qbuf, kbuf, vbuf, aout);
  gemm128<2><<<dim3(8, 16), dim3(256), 0, stream>>>(aout, Wo16, outp, nullptr, 0);
}

// Round 5
// 579.431 us; speedup vs baseline: 1.0561x; 1.0469x over previous
//
#include <hip/hip_runtime.h>
#include <cstdint>
#include <cstddef>

#define B_SZ 8
#define N1 4096
#define N2 256
#define LTOT 4352          // N1 + N2
#define DIMD 1024
#define HEADS 16
#define DH 64
#define MKV (B_SZ * LTOT)  // 34816
#define ATILE 64
#define AITERS (LTOT / ATILE)  // 68

typedef _Float16 f16;
typedef f16 f16x4_t __attribute__((ext_vector_type(4)));
typedef f16 f16x8_t __attribute__((ext_vector_type(8)));
typedef float f32x4_t __attribute__((ext_vector_type(4)));

// async global -> LDS, 16B per lane. LDS dest is wave-uniform base + lane*16.
__device__ __forceinline__ void g2l16(const void* g, void* l) {
  __builtin_amdgcn_global_load_lds(
      (__attribute__((address_space(1))) void*)g,
      (__attribute__((address_space(3))) void*)l, 16, 0, 0);
}

// ---------------------------------------------------------------------------
// Kernel 1: layernorm (+ latent modulation), f32 -> f16, into concat kv_in
// ---------------------------------------------------------------------------
__global__ __launch_bounds__(256) void ln_mod_kernel(
    const float* __restrict__ x, const float* __restrict__ lat,
    const float* __restrict__ shift, const float* __restrict__ scale,
    const float* __restrict__ ln1w, const float* __restrict__ ln1b,
    const float* __restrict__ ln2w, const float* __restrict__ ln2b,
    f16* __restrict__ kv_in) {
  const int row = blockIdx.x;
  const int b = row / LTOT;
  const int n = row - b * LTOT;
  const int tid = threadIdx.x;
  const bool is_lat = (n >= N1);
  const float* src = is_lat ? (lat + (size_t)(b * N2 + (n - N1)) * DIMD)
                            : (x + (size_t)(b * N1 + n) * DIMD);
  float4 v = ((const float4*)src)[tid];
  float s = v.x + v.y + v.z + v.w;
  float s2 = v.x * v.x + v.y * v.y + v.z * v.z + v.w * v.w;
#pragma unroll
  for (int m = 1; m <= 32; m <<= 1) {
    s += __shfl_xor(s, m, 64);
    s2 += __shfl_xor(s2, m, 64);
  }
  __shared__ float red[8];
  const int wave = tid >> 6;
  if ((tid & 63) == 0) { red[wave * 2] = s; red[wave * 2 + 1] = s2; }
  __syncthreads();
  s = red[0] + red[2] + red[4] + red[6];
  s2 = red[1] + red[3] + red[5] + red[7];
  const float mean = s * (1.0f / DIMD);
  const float var = fmaxf(s2 * (1.0f / DIMD) - mean * mean, 0.0f);
  const float rstd = rsqrtf(var + 1e-5f);
  const float4 w4 = ((const float4*)(is_lat ? ln2w : ln1w))[tid];
  const float4 b4 = ((const float4*)(is_lat ? ln2b : ln1b))[tid];
  float y0 = (v.x - mean) * rstd * w4.x + b4.x;
  float y1 = (v.y - mean) * rstd * w4.y + b4.y;
  float y2 = (v.z - mean) * rstd * w4.z + b4.z;
  float y3 = (v.w - mean) * rstd * w4.w + b4.w;
  if (is_lat) {
    float4 sc = ((const float4*)(scale + (size_t)b * DIMD))[tid];
    float4 sh = ((const float4*)(shift + (size_t)b * DIMD))[tid];
    y0 = y0 * (1.0f + sc.x) + sh.x;
    y1 = y1 * (1.0f + sc.y) + sh.y;
    y2 = y2 * (1.0f + sc.z) + sh.z;
    y3 = y3 * (1.0f + sc.w) + sh.w;
  }
  f16x4_t o = {(f16)y0, (f16)y1, (f16)y2, (f16)y3};
  *(f16x4_t*)(kv_in + (size_t)row * DIMD + tid * 4) = o;
}

// ---------------------------------------------------------------------------
// Kernel 2: f32 -> f16 cast (weights)
// ---------------------------------------------------------------------------
__global__ __launch_bounds__(256) void cast_kernel(const float* __restrict__ in,
                                                   f16* __restrict__ out, int n4) {
  const int i = blockIdx.x * 256 + threadIdx.x;
  if (i < n4) {
    float4 v = ((const float4*)in)[i];
    f16x4_t o = {(f16)v.x, (f16)v.y, (f16)v.z, (f16)v.w};
    ((f16x4_t*)out)[i] = o;
  }
}

// ---------------------------------------------------------------------------
// Kernel 3: 128x128-tile GEMM, C = A (MxK rowmajor f16) * BT (NxK rowmajor f16)
// m97 structure: BK=32, global_load_lds 16B staging, 16x16x32 f16 MFMA.
// Grid (nt, mt), nt fastest for A-tile L2 reuse.
// MODE 0: kv GEMM -> scatter to k_buf (b,h,n,d) / v_buf transposed (b,h,d,n)
// MODE 1: q GEMM (A rows = latent rows inside kv_in) -> q_buf (b,h,n,d)
// MODE 2: out GEMM -> f32 d_out
// ---------------------------------------------------------------------------
template <int MODE>
__global__ __launch_bounds__(256) void gemm128(
    const f16* __restrict__ A0, const f16* __restrict__ BT,
    void* __restrict__ out0, void* __restrict__ out1, int nt_base) {
  const int mt = blockIdx.y, nt = nt_base + blockIdx.x;
  const f16* Abase;
  if (MODE == 1) {
    const int bb = mt >> 1;
    Abase = A0 + ((size_t)(bb * LTOT + N1 + (mt & 1) * 128)) * DIMD;
  } else {
    Abase = A0 + (size_t)mt * 128 * DIMD;
  }
  const f16* Bbase = BT + (size_t)nt * 128 * DIMD;
  __shared__ alignas(16) f16 As[128 * 32];
  __shared__ alignas(16) f16 Bs[128 * 32];
  const int tid = threadIdx.x;
  const int wave = tid >> 6, lane = tid & 63;
  const int wm = (wave & 1) * 64, wn = (wave >> 1) * 64;
  const int lrow = lane >> 2, lcol = (lane & 3) * 8;
  const int r16 = lane & 15, g8 = (lane >> 4) * 8, q4 = (lane >> 4) * 4;
  f32x4_t acc[4][4] = {};
  for (int k0 = 0; k0 < DIMD; k0 += 32) {
    __syncthreads();
    g2l16(Abase + (size_t)(wave * 16 + lrow) * DIMD + k0 + lcol, &As[(wave * 16) * 32]);
    g2l16(Abase + (size_t)(64 + wave * 16 + lrow) * DIMD + k0 + lcol, &As[(64 + wave * 16) * 32]);
    g2l16(Bbase + (size_t)(wave * 16 + lrow) * DIMD + k0 + lcol, &Bs[(wave * 16) * 32]);
    g2l16(Bbase + (size_t)(64 + wave * 16 + lrow) * DIMD + k0 + lcol, &Bs[(64 + wave * 16) * 32]);
    __syncthreads();
    f16x8_t a[4], bf[4];
#pragma unroll
    for (int i = 0; i < 4; i++)
      a[i] = *(const f16x8_t*)&As[(wm + i * 16 + r16) * 32 + g8];
#pragma unroll
    for (int j = 0; j < 4; j++)
      bf[j] = *(const f16x8_t*)&Bs[(wn + j * 16 + r16) * 32 + g8];
#pragma unroll
    for (int i = 0; i < 4; i++)
#pragma unroll
      for (int j = 0; j < 4; j++)
        acc[i][j] = __builtin_amdgcn_mfma_f32_16x16x32_f16(a[i], bf[j], acc[i][j], 0, 0, 0);
  }

  if constexpr (MODE == 0) {
    const int m0 = mt * 128;
    const int b = m0 / LTOT;
    const int n0 = m0 - b * LTOT;
    const int e0 = nt * 128;
    if (e0 < 1024) {  // k half: layout ((b*16+h)*4352 + n)*64 + d
      f16* kbuf = (f16*)out0;
#pragma unroll
      for (int i = 0; i < 4; i++) {
        const int n_base = n0 + wm + i * 16 + q4;
#pragma unroll
        for (int j = 0; j < 4; j++) {
          const int e = e0 + wn + j * 16 + r16;
          const int h = e >> 6, d = e & 63;
          const size_t base = ((size_t)(b * HEADS + h) * LTOT);
#pragma unroll
          for (int r = 0; r < 4; r++)
            kbuf[(base + n_base + r) * DH + d] = (f16)acc[i][j][r];
        }
      }
    } else {  // v half, transposed: ((b*16+h)*64 + d)*4352 + n
      f16* vbuf = (f16*)out1;
      const int e0v = e0 - 1024;
#pragma unroll
      for (int i = 0; i < 4; i++) {
        const int n_base = n0 + wm + i * 16 + q4;
#pragma unroll
        for (int j = 0; j < 4; j++) {
          const int e = e0v + wn + j * 16 + r16;
          const int h = e >> 6, d = e & 63;
          f16x4_t pk = {(f16)acc[i][j][0], (f16)acc[i][j][1],
                        (f16)acc[i][j][2], (f16)acc[i][j][3]};
          *(f16x4_t*)&vbuf[((size_t)(b * HEADS + h) * DH + d) * LTOT + n_base] = pk;
        }
      }
    }
  } else if constexpr (MODE == 1) {  // q: ((b*16+h)*256 + n)*64 + d
    f16* qbuf = (f16*)out0;
    const int b = mt >> 1;
#pragma unroll
    for (int i = 0; i < 4; i++) {
      const int n_base = (mt & 1) * 128 + wm + i * 16 + q4;
#pragma unroll
      for (int j = 0; j < 4; j++) {
        const int e = nt * 128 + wn + j * 16 + r16;
        const int h = e >> 6, d = e & 63;
#pragma unroll
        for (int r = 0; r < 4; r++)
          qbuf[((size_t)(b * HEADS + h) * N2 + n_base + r) * DH + d] = (f16)acc[i][j][r];
      }
    }
  } else {  // final output, f32
    float* outp = (float*)out0;
    const int m0 = mt * 128;
#pragma unroll
    for (int i = 0; i < 4; i++) {
#pragma unroll
      for (int j = 0; j < 4; j++) {
        const int col = nt * 128 + wn + j * 16 + r16;
#pragma unroll
        for (int r = 0; r < 4; r++)
          outp[(size_t)(m0 + wm + i * 16 + q4 + r) * DIMD + col] = acc[i][j][r];
      }
    }
  }
}

// ---------------------------------------------------------------------------
// Kernel 4: flash attention v3 — 512 threads (8 waves, 2 waves/SIMD), K-tile
// 64, depth-2 async K/V double-buffer with raw vmcnt/s_barrier (AITER-style:
// prefetch stays in flight across the barrier; never drain to vmcnt(0)).
//   S^T = K * Q^T  (A = K tile, B^T = Q)    O^T = Vt * P^T  (A = Vt, B^T = P)
// Wave w owns q-cols w*16..w*16+15. P per-wave-private, overlays the Q region
// (Q is register-resident after the prologue). LDS = 50.4 KB.
// ---------------------------------------------------------------------------
__global__ __launch_bounds__(512, 1) void attn_kernel(
    const f16* __restrict__ qbuf, const f16* __restrict__ kbuf,
    const f16* __restrict__ vbuf, f16* __restrict__ attn_out) {
  const int bh = blockIdx.x >> 1;
  const int qt = blockIdx.x & 1;
  const int b = bh >> 4, h = bh & 15;
  const f16* qg = qbuf + ((size_t)bh * N2 + qt * 128) * DH;
  const f16* kg = kbuf + (size_t)bh * LTOT * DH;
  const f16* vg = vbuf + (size_t)bh * DH * LTOT;

  __shared__ alignas(16) f16 Ks[2][4096];  // 2 bufs x (2 d-panels x 64k x 32)
  __shared__ alignas(16) f16 Vs[2][4096];  // 2 bufs x (2 k-panels x 64d x 32)
  __shared__ alignas(16) f16 QP[9216];     // Q (8192, prologue) / P (per-wave)

  const int tid = threadIdx.x, wave = tid >> 6, lane = tid & 63;
  const int lrow = lane >> 2, lcol = (lane & 3) * 8;
  const int r16 = lane & 15, g8 = (lane >> 4) * 8, q4 = (lane >> 4) * 4;
  f16* Ps = &QP[wave * 1152];  // 16 q-rows x 72 halves, wave-private

  // prologue: stage Q (2 chunks/wave)
#pragma unroll
  for (int i = 0; i < 2; i++) {
    const int c = wave * 2 + i, s = c >> 3, rb = (c & 7) * 16;
    g2l16(qg + (size_t)(rb + lrow) * DH + s * 32 + lcol, &QP[s * 4096 + rb * 32]);
  }
  // stage K/V tile kt into buf (1 K-chunk + 1 V-chunk per wave = 2 loads)
  auto stage = [&](int kt, int buf) {
    const int s = wave >> 2, rb = (wave & 3) * 16;
    g2l16(kg + (size_t)(kt * ATILE + rb + lrow) * DH + s * 32 + lcol,
          &Ks[buf][s * 2048 + rb * 32]);
    g2l16(vg + (size_t)(rb + lrow) * LTOT + kt * ATILE + s * 32 + lcol,
          &Vs[buf][s * 2048 + rb * 32]);
  };
  stage(0, 0);
  stage(1, 1);
  asm volatile("s_waitcnt vmcnt(4)" ::: "memory");  // Q (oldest 2) landed
  asm volatile("s_barrier" ::: "memory");
  f16x8_t bQ[2];
#pragma unroll
  for (int s = 0; s < 2; s++)
    bQ[s] = *(const f16x8_t*)&QP[s * 4096 + (wave * 16 + r16) * 32 + g8];
  asm volatile("s_waitcnt lgkmcnt(0)" ::: "memory");  // bQ in regs before P overlays Q

  f32x4_t oacc[4] = {};
  float mrow = -1e30f, lsum = 0.0f;
  const float SCL = 0.125f * 1.44269504089f;  // attn_scale^2 * log2(e)

  for (int kt = 0; kt < AITERS; kt++) {
    const int cur = kt & 1;
    asm volatile("s_waitcnt vmcnt(2)" ::: "memory");  // buf[cur] landed; next tile in flight
    asm volatile("s_barrier" ::: "memory");
    // S^T = K * Q^T : 64 keys x 16 q per wave
    f32x4_t sacc[4] = {};
#pragma unroll
    for (int s = 0; s < 2; s++) {
      f16x8_t aK[4];
#pragma unroll
      for (int i = 0; i < 4; i++)
        aK[i] = *(const f16x8_t*)&Ks[cur][s * 2048 + (i * 16 + r16) * 32 + g8];
#pragma unroll
      for (int i = 0; i < 4; i++)
        sacc[i] = __builtin_amdgcn_mfma_f32_16x16x32_f16(aK[i], bQ[s], sacc[i], 0, 0, 0);
    }
    // online softmax (base-2); lane q-col = r16
    float vmax = -1e30f;
#pragma unroll
    for (int i = 0; i < 4; i++)
#pragma unroll
      for (int r = 0; r < 4; r++) vmax = fmaxf(vmax, sacc[i][r]);
    vmax = fmaxf(vmax, __shfl_xor(vmax, 16, 64));
    vmax = fmaxf(vmax, __shfl_xor(vmax, 32, 64));
    const float m_new = fmaxf(mrow, SCL * vmax);
    const float alpha = exp2f(mrow - m_new);
    float psum = 0.0f;
#pragma unroll
    for (int i = 0; i < 4; i++) {
      f16x4_t pk;
#pragma unroll
      for (int r = 0; r < 4; r++) {
        const float p = exp2f(SCL * sacc[i][r] - m_new);
        psum += p;
        pk[r] = (f16)p;
      }
      *(f16x4_t*)&Ps[r16 * 72 + i * 16 + q4] = pk;
    }
    psum += __shfl_xor(psum, 16, 64);
    psum += __shfl_xor(psum, 32, 64);
    lsum = lsum * alpha + psum;
    mrow = m_new;
#pragma unroll
    for (int id = 0; id < 4; id++) oacc[id] *= alpha;
    // O^T += Vt * P^T (P wave-private; DS in-order per wave)
#pragma unroll
    for (int s2 = 0; s2 < 2; s2++) {
      f16x8_t aV[4];
#pragma unroll
      for (int id = 0; id < 4; id++)
        aV[id] = *(const f16x8_t*)&Vs[cur][s2 * 2048 + (id * 16 + r16) * 32 + g8];
      const f16x8_t bP = *(const f16x8_t*)&Ps[r16 * 72 + s2 * 32 + g8];
#pragma unroll
      for (int id = 0; id < 4; id++)
        oacc[id] = __builtin_amdgcn_mfma_f32_16x16x32_f16(aV[id], bP, oacc[id], 0, 0, 0);
    }
    asm volatile("s_waitcnt lgkmcnt(0)" ::: "memory");  // buf[cur] reads done
    asm volatile("s_barrier" ::: "memory");             // all waves done with buf[cur]
    if (kt + 2 < AITERS) stage(kt + 2, cur);
  }
  // epilogue: attn_out[(b*256+q)*1024 + h*64 + d]
  const float inv = 1.0f / lsum;
  const int q = qt * 128 + wave * 16 + r16;
  const size_t rowbase = ((size_t)(b * N2 + q)) * DIMD + h * DH;
#pragma unroll
  for (int id = 0; id < 4; id++) {
    f16x4_t pk;
#pragma unroll
    for (int r = 0; r < 4; r++) pk[r] = (f16)(oacc[id][r] * inv);
    *(f16x4_t*)&attn_out[rowbase + id * 16 + q4] = pk;
  }
}

// ---------------------------------------------------------------------------
extern "C" void kernel_launch(void* const* d_in, const int* in_sizes, int n_in,
                              void* d_out, int out_size, void* d_ws, size_t ws_size,
                              hipStream_t stream) {
  const float* x     = (const float*)d_in[0];
  const float* lat   = (const float*)d_in[1];
  const float* shift = (const float*)d_in[2];
  const float* scale = (const float*)d_in[3];
  const float* ln1w  = (const float*)d_in[4];
  const float* ln1b  = (const float*)d_in[5];
  const float* ln2w  = (const float*)d_in[6];
  const float* ln2b  = (const float*)d_in[7];
  const float* Wq    = (const float*)d_in[8];
  const float* Wkv   = (const float*)d_in[9];
  const float* Wo    = (const float*)d_in[10];
  float* outp = (float*)d_out;

  char* ws = (char*)d_ws;
  f16* kv_in = (f16*)ws;                 ws += (size_t)MKV * DIMD * 2;          // 68 MB
  f16* Wq16  = (f16*)ws;                 ws += (size_t)1024 * 1024 * 2;         // 2 MB
  f16* Wkv16 = (f16*)ws;                 ws += (size_t)2048 * 1024 * 2;         // 4 MB
  f16* Wo16  = (f16*)ws;                 ws += (size_t)1024 * 1024 * 2;         // 2 MB
  f16* qbuf  = (f16*)ws;                 ws += (size_t)B_SZ * HEADS * N2 * DH * 2;   // 4 MB
  f16* kbuf  = (f16*)ws;                 ws += (size_t)B_SZ * HEADS * LTOT * DH * 2; // 68 MB
  f16* vbuf  = (f16*)ws;                 ws += (size_t)B_SZ * HEADS * LTOT * DH * 2; // 68 MB
  f16* aout  = (f16*)ws;                 ws += (size_t)B_SZ * N2 * DIMD * 2;         // 4 MB

  ln_mod_kernel<<<dim3(MKV), dim3(256), 0, stream>>>(x, lat, shift, scale, ln1w,
                                                     ln1b, ln2w, ln2b, kv_in);
  cast_kernel<<<dim3(1024), dim3(256), 0, stream>>>(Wq, Wq16, 1024 * 1024 / 4);
  cast_kernel<<<dim3(2048), dim3(256), 0, stream>>>(Wkv, Wkv16, 2048 * 1024 / 4);
  cast_kernel<<<dim3(1024), dim3(256), 0, stream>>>(Wo, Wo16, 1024 * 1024 / 4);

  gemm128<0><<<dim3(8, MKV / 128), dim3(256), 0, stream>>>(kv_in, Wkv16, kbuf, vbuf, 0);
  gemm128<0><<<dim3(8, MKV / 128), dim3(256), 0, stream>>>(kv_in, Wkv16, kbuf, vbuf, 8);
  gemm128<1><<<dim3(8, 16), dim3(256), 0, stream>>>(kv_in, Wq16, qbuf, nullptr, 0);
  attn_kernel<<<dim3(256), dim3(512), 0, stream>>>(qbuf, kbuf, vbuf, aout);
  gemm128<2><<<dim3(8, 16), dim3(256), 0, stream>>>(aout, Wo16, outp, nullptr, 0);
}

// Round 6
// 539.836 us; speedup vs baseline: 1.1336x; 1.0733x over previous
//
#include <hip/hip_runtime.h>
#include <cstdint>
#include <cstddef>

#define B_SZ 8
#define N1 4096
#define N2 256
#define LTOT 4352          // N1 + N2
#define DIMD 1024
#define HEADS 16
#define DH 64
#define MKV (B_SZ * LTOT)  // 34816
#define ATILE 64
#define AITERS (LTOT / ATILE)  // 68
#define G0_BLOCKS 4352         // 272 mt x 16 nt
#define MT_PER_XCD 34          // 272 / 8

typedef _Float16 f16;
typedef f16 f16x4_t __attribute__((ext_vector_type(4)));
typedef f16 f16x8_t __attribute__((ext_vector_type(8)));
typedef float f32x4_t __attribute__((ext_vector_type(4)));

// async global -> LDS, 16B per lane. LDS dest is wave-uniform base + lane*16.
__device__ __forceinline__ void g2l16(const void* g, void* l) {
  __builtin_amdgcn_global_load_lds(
      (__attribute__((address_space(1))) void*)g,
      (__attribute__((address_space(3))) void*)l, 16, 0, 0);
}

// ---------------------------------------------------------------------------
// Kernel 1: prep = layernorm/modulation (blocks 0..MKV-1) + weight casts
// (blocks MKV..MKV+4095). One dispatch replaces four.
// ---------------------------------------------------------------------------
__global__ __launch_bounds__(256) void prep_kernel(
    const float* __restrict__ x, const float* __restrict__ lat,
    const float* __restrict__ shift, const float* __restrict__ scale,
    const float* __restrict__ ln1w, const float* __restrict__ ln1b,
    const float* __restrict__ ln2w, const float* __restrict__ ln2b,
    const float* __restrict__ Wq, const float* __restrict__ Wkv,
    const float* __restrict__ Wo, f16* __restrict__ kv_in,
    f16* __restrict__ Wq16, f16* __restrict__ Wkv16, f16* __restrict__ Wo16) {
  const int bid = blockIdx.x;
  const int tid = threadIdx.x;
  if (bid >= MKV) {  // weight casts: 1024 f32 per block
    const int c = bid - MKV;
    const float* src;
    f16* dst;
    int off;
    if (c < 1024) { src = Wq; dst = Wq16; off = c; }
    else if (c < 3072) { src = Wkv; dst = Wkv16; off = c - 1024; }
    else { src = Wo; dst = Wo16; off = c - 3072; }
    const int i = off * 256 + tid;
    float4 v = ((const float4*)src)[i];
    f16x4_t o = {(f16)v.x, (f16)v.y, (f16)v.z, (f16)v.w};
    ((f16x4_t*)dst)[i] = o;
    return;
  }
  const int row = bid;
  const int b = row / LTOT;
  const int n = row - b * LTOT;
  const bool is_lat = (n >= N1);
  const float* src = is_lat ? (lat + (size_t)(b * N2 + (n - N1)) * DIMD)
                            : (x + (size_t)(b * N1 + n) * DIMD);
  float4 v = ((const float4*)src)[tid];
  float s = v.x + v.y + v.z + v.w;
  float s2 = v.x * v.x + v.y * v.y + v.z * v.z + v.w * v.w;
#pragma unroll
  for (int m = 1; m <= 32; m <<= 1) {
    s += __shfl_xor(s, m, 64);
    s2 += __shfl_xor(s2, m, 64);
  }
  __shared__ float red[8];
  const int wave = tid >> 6;
  if ((tid & 63) == 0) { red[wave * 2] = s; red[wave * 2 + 1] = s2; }
  __syncthreads();
  s = red[0] + red[2] + red[4] + red[6];
  s2 = red[1] + red[3] + red[5] + red[7];
  const float mean = s * (1.0f / DIMD);
  const float var = fmaxf(s2 * (1.0f / DIMD) - mean * mean, 0.0f);
  const float rstd = rsqrtf(var + 1e-5f);
  const float4 w4 = ((const float4*)(is_lat ? ln2w : ln1w))[tid];
  const float4 b4 = ((const float4*)(is_lat ? ln2b : ln1b))[tid];
  float y0 = (v.x - mean) * rstd * w4.x + b4.x;
  float y1 = (v.y - mean) * rstd * w4.y + b4.y;
  float y2 = (v.z - mean) * rstd * w4.z + b4.z;
  float y3 = (v.w - mean) * rstd * w4.w + b4.w;
  if (is_lat) {
    float4 sc = ((const float4*)(scale + (size_t)b * DIMD))[tid];
    float4 sh = ((const float4*)(shift + (size_t)b * DIMD))[tid];
    y0 = y0 * (1.0f + sc.x) + sh.x;
    y1 = y1 * (1.0f + sc.y) + sh.y;
    y2 = y2 * (1.0f + sc.z) + sh.z;
    y3 = y3 * (1.0f + sc.w) + sh.w;
  }
  f16x4_t o = {(f16)y0, (f16)y1, (f16)y2, (f16)y3};
  *(f16x4_t*)(kv_in + (size_t)row * DIMD + tid * 4) = o;
}

// ---------------------------------------------------------------------------
// Kernel 2: fused pre-attention GEMMs (kv GEMM + q GEMM) in ONE dispatch.
// 128x128 tiles, BK=32, global_load_lds 16B staging, 16x16x32 f16 MFMA.
// Blocks 0..4351: kv GEMM, XCD-swizzled (hw maps id%8 -> XCD): XCD x owns
//   mt in [34x, 34x+34), sweeping all 16 nt per mt -> A-tile read 16x from
//   the SAME XCD's L2; B (4 MB) L2/L3-resident per XCD.
// Blocks 4352..4479: q GEMM (A rows = latent rows inside kv_in).
// ---------------------------------------------------------------------------
__global__ __launch_bounds__(256) void gemm_pre(
    const f16* __restrict__ kv_in, const f16* __restrict__ Wkv16,
    const f16* __restrict__ Wq16, f16* __restrict__ kbuf,
    f16* __restrict__ vbuf, f16* __restrict__ qbuf) {
  const int id = blockIdx.x;
  const bool is_kv = (id < G0_BLOCKS);
  int mt, nt;
  const f16 *Abase, *Bbase;
  if (is_kv) {
    const int xcd = id & 7, l = id >> 3;
    mt = xcd * MT_PER_XCD + (l >> 4);
    nt = l & 15;
    Abase = kv_in + (size_t)mt * 128 * DIMD;
    Bbase = Wkv16 + (size_t)nt * 128 * DIMD;
  } else {
    const int id2 = id - G0_BLOCKS;
    mt = id2 >> 3;  // 0..15
    nt = id2 & 7;
    const int bb = mt >> 1;
    Abase = kv_in + ((size_t)(bb * LTOT + N1 + (mt & 1) * 128)) * DIMD;
    Bbase = Wq16 + (size_t)nt * 128 * DIMD;
  }
  __shared__ alignas(16) f16 As[128 * 32];
  __shared__ alignas(16) f16 Bs[128 * 32];
  const int tid = threadIdx.x;
  const int wave = tid >> 6, lane = tid & 63;
  const int wm = (wave & 1) * 64, wn = (wave >> 1) * 64;
  const int lrow = lane >> 2, lcol = (lane & 3) * 8;
  const int r16 = lane & 15, g8 = (lane >> 4) * 8, q4 = (lane >> 4) * 4;
  f32x4_t acc[4][4] = {};
  for (int k0 = 0; k0 < DIMD; k0 += 32) {
    __syncthreads();
    g2l16(Abase + (size_t)(wave * 16 + lrow) * DIMD + k0 + lcol, &As[(wave * 16) * 32]);
    g2l16(Abase + (size_t)(64 + wave * 16 + lrow) * DIMD + k0 + lcol, &As[(64 + wave * 16) * 32]);
    g2l16(Bbase + (size_t)(wave * 16 + lrow) * DIMD + k0 + lcol, &Bs[(wave * 16) * 32]);
    g2l16(Bbase + (size_t)(64 + wave * 16 + lrow) * DIMD + k0 + lcol, &Bs[(64 + wave * 16) * 32]);
    __syncthreads();
    f16x8_t a[4], bf[4];
#pragma unroll
    for (int i = 0; i < 4; i++)
      a[i] = *(const f16x8_t*)&As[(wm + i * 16 + r16) * 32 + g8];
#pragma unroll
    for (int j = 0; j < 4; j++)
      bf[j] = *(const f16x8_t*)&Bs[(wn + j * 16 + r16) * 32 + g8];
#pragma unroll
    for (int i = 0; i < 4; i++)
#pragma unroll
      for (int j = 0; j < 4; j++)
        acc[i][j] = __builtin_amdgcn_mfma_f32_16x16x32_f16(a[i], bf[j], acc[i][j], 0, 0, 0);
  }

  if (is_kv) {
    const int m0 = mt * 128;
    const int b = m0 / LTOT;
    const int n0 = m0 - b * LTOT;
    const int e0 = nt * 128;
    if (e0 < 1024) {  // k half: ((b*16+h)*4352 + n)*64 + d
#pragma unroll
      for (int i = 0; i < 4; i++) {
        const int n_base = n0 + wm + i * 16 + q4;
#pragma unroll
        for (int j = 0; j < 4; j++) {
          const int e = e0 + wn + j * 16 + r16;
          const int h = e >> 6, d = e & 63;
          const size_t base = ((size_t)(b * HEADS + h) * LTOT);
#pragma unroll
          for (int r = 0; r < 4; r++)
            kbuf[(base + n_base + r) * DH + d] = (f16)acc[i][j][r];
        }
      }
    } else {  // v half, transposed: ((b*16+h)*64 + d)*4352 + n
      const int e0v = e0 - 1024;
#pragma unroll
      for (int i = 0; i < 4; i++) {
        const int n_base = n0 + wm + i * 16 + q4;
#pragma unroll
        for (int j = 0; j < 4; j++) {
          const int e = e0v + wn + j * 16 + r16;
          const int h = e >> 6, d = e & 63;
          f16x4_t pk = {(f16)acc[i][j][0], (f16)acc[i][j][1],
                        (f16)acc[i][j][2], (f16)acc[i][j][3]};
          *(f16x4_t*)&vbuf[((size_t)(b * HEADS + h) * DH + d) * LTOT + n_base] = pk;
        }
      }
    }
  } else {  // q: ((b*16+h)*256 + n)*64 + d
    const int b = mt >> 1;
#pragma unroll
    for (int i = 0; i < 4; i++) {
      const int n_base = (mt & 1) * 128 + wm + i * 16 + q4;
#pragma unroll
      for (int j = 0; j < 4; j++) {
        const int e = nt * 128 + wn + j * 16 + r16;
        const int h = e >> 6, d = e & 63;
#pragma unroll
        for (int r = 0; r < 4; r++)
          qbuf[((size_t)(b * HEADS + h) * N2 + n_base + r) * DH + d] = (f16)acc[i][j][r];
      }
    }
  }
}

// ---------------------------------------------------------------------------
// Kernel 3 (post-attn): out GEMM -> f32 d_out. 128x128 tiles, grid (8,16).
// ---------------------------------------------------------------------------
__global__ __launch_bounds__(256) void gemm_out(
    const f16* __restrict__ A0, const f16* __restrict__ BT,
    float* __restrict__ outp) {
  const int mt = blockIdx.y, nt = blockIdx.x;
  const f16* Abase = A0 + (size_t)mt * 128 * DIMD;
  const f16* Bbase = BT + (size_t)nt * 128 * DIMD;
  __shared__ alignas(16) f16 As[128 * 32];
  __shared__ alignas(16) f16 Bs[128 * 32];
  const int tid = threadIdx.x;
  const int wave = tid >> 6, lane = tid & 63;
  const int wm = (wave & 1) * 64, wn = (wave >> 1) * 64;
  const int lrow = lane >> 2, lcol = (lane & 3) * 8;
  const int r16 = lane & 15, g8 = (lane >> 4) * 8, q4 = (lane >> 4) * 4;
  f32x4_t acc[4][4] = {};
  for (int k0 = 0; k0 < DIMD; k0 += 32) {
    __syncthreads();
    g2l16(Abase + (size_t)(wave * 16 + lrow) * DIMD + k0 + lcol, &As[(wave * 16) * 32]);
    g2l16(Abase + (size_t)(64 + wave * 16 + lrow) * DIMD + k0 + lcol, &As[(64 + wave * 16) * 32]);
    g2l16(Bbase + (size_t)(wave * 16 + lrow) * DIMD + k0 + lcol, &Bs[(wave * 16) * 32]);
    g2l16(Bbase + (size_t)(64 + wave * 16 + lrow) * DIMD + k0 + lcol, &Bs[(64 + wave * 16) * 32]);
    __syncthreads();
    f16x8_t a[4], bf[4];
#pragma unroll
    for (int i = 0; i < 4; i++)
      a[i] = *(const f16x8_t*)&As[(wm + i * 16 + r16) * 32 + g8];
#pragma unroll
    for (int j = 0; j < 4; j++)
      bf[j] = *(const f16x8_t*)&Bs[(wn + j * 16 + r16) * 32 + g8];
#pragma unroll
    for (int i = 0; i < 4; i++)
#pragma unroll
      for (int j = 0; j < 4; j++)
        acc[i][j] = __builtin_amdgcn_mfma_f32_16x16x32_f16(a[i], bf[j], acc[i][j], 0, 0, 0);
  }
  const int m0 = mt * 128;
#pragma unroll
  for (int i = 0; i < 4; i++) {
#pragma unroll
    for (int j = 0; j < 4; j++) {
      const int col = nt * 128 + wn + j * 16 + r16;
#pragma unroll
      for (int r = 0; r < 4; r++)
        outp[(size_t)(m0 + wm + i * 16 + q4 + r) * DIMD + col] = acc[i][j][r];
    }
  }
}

// ---------------------------------------------------------------------------
// Kernel 4: flash attention — 512 threads (8 waves), K-tile 64, depth-2 async
// K/V double-buffer with raw vmcnt/s_barrier. launch_bounds(512,2) caps VGPR
// at 128 -> 2 blocks/CU (LDS 50.4 KB x2 = 101 KB < 160).
// ---------------------------------------------------------------------------
__global__ __launch_bounds__(512, 2) void attn_kernel(
    const f16* __restrict__ qbuf, const f16* __restrict__ kbuf,
    const f16* __restrict__ vbuf, f16* __restrict__ attn_out) {
  const int bh = blockIdx.x >> 1;
  const int qt = blockIdx.x & 1;
  const int b = bh >> 4, h = bh & 15;
  const f16* qg = qbuf + ((size_t)bh * N2 + qt * 128) * DH;
  const f16* kg = kbuf + (size_t)bh * LTOT * DH;
  const f16* vg = vbuf + (size_t)bh * DH * LTOT;

  __shared__ alignas(16) f16 Ks[2][4096];  // 2 bufs x (2 d-panels x 64k x 32)
  __shared__ alignas(16) f16 Vs[2][4096];  // 2 bufs x (2 k-panels x 64d x 32)
  __shared__ alignas(16) f16 QP[9216];     // Q (8192, prologue) / P (per-wave)

  const int tid = threadIdx.x, wave = tid >> 6, lane = tid & 63;
  const int lrow = lane >> 2, lcol = (lane & 3) * 8;
  const int r16 = lane & 15, g8 = (lane >> 4) * 8, q4 = (lane >> 4) * 4;
  f16* Ps = &QP[wave * 1152];  // 16 q-rows x 72 halves, wave-private

  // prologue: stage Q (2 chunks/wave)
#pragma unroll
  for (int i = 0; i < 2; i++) {
    const int c = wave * 2 + i, s = c >> 3, rb = (c & 7) * 16;
    g2l16(qg + (size_t)(rb + lrow) * DH + s * 32 + lcol, &QP[s * 4096 + rb * 32]);
  }
  // stage K/V tile kt into buf (1 K-chunk + 1 V-chunk per wave = 2 loads)
  auto stage = [&](int kt, int buf) {
    const int s = wave >> 2, rb = (wave & 3) * 16;
    g2l16(kg + (size_t)(kt * ATILE + rb + lrow) * DH + s * 32 + lcol,
          &Ks[buf][s * 2048 + rb * 32]);
    g2l16(vg + (size_t)(rb + lrow) * LTOT + kt * ATILE + s * 32 + lcol,
          &Vs[buf][s * 2048 + rb * 32]);
  };
  stage(0, 0);
  stage(1, 1);
  asm volatile("s_waitcnt vmcnt(4)" ::: "memory");  // Q (oldest 2) landed
  asm volatile("s_barrier" ::: "memory");
  f16x8_t bQ[2];
#pragma unroll
  for (int s = 0; s < 2; s++)
    bQ[s] = *(const f16x8_t*)&QP[s * 4096 + (wave * 16 + r16) * 32 + g8];
  asm volatile("s_waitcnt lgkmcnt(0)" ::: "memory");  // bQ in regs before P overlays Q

  f32x4_t oacc[4] = {};
  float mrow = -1e30f, lsum = 0.0f;
  const float SCL = 0.125f * 1.44269504089f;  // attn_scale^2 * log2(e)

  for (int kt = 0; kt < AITERS; kt++) {
    const int cur = kt & 1;
    asm volatile("s_waitcnt vmcnt(2)" ::: "memory");  // buf[cur] landed; next in flight
    asm volatile("s_barrier" ::: "memory");
    // S^T = K * Q^T : 64 keys x 16 q per wave
    f32x4_t sacc[4] = {};
#pragma unroll
    for (int s = 0; s < 2; s++) {
      f16x8_t aK[4];
#pragma unroll
      for (int i = 0; i < 4; i++)
        aK[i] = *(const f16x8_t*)&Ks[cur][s * 2048 + (i * 16 + r16) * 32 + g8];
#pragma unroll
      for (int i = 0; i < 4; i++)
        sacc[i] = __builtin_amdgcn_mfma_f32_16x16x32_f16(aK[i], bQ[s], sacc[i], 0, 0, 0);
    }
    // online softmax (base-2); lane q-col = r16
    float vmax = -1e30f;
#pragma unroll
    for (int i = 0; i < 4; i++)
#pragma unroll
      for (int r = 0; r < 4; r++) vmax = fmaxf(vmax, sacc[i][r]);
    vmax = fmaxf(vmax, __shfl_xor(vmax, 16, 64));
    vmax = fmaxf(vmax, __shfl_xor(vmax, 32, 64));
    const float m_new = fmaxf(mrow, SCL * vmax);
    const float alpha = exp2f(mrow - m_new);
    float psum = 0.0f;
#pragma unroll
    for (int i = 0; i < 4; i++) {
      f16x4_t pk;
#pragma unroll
      for (int r = 0; r < 4; r++) {
        const float p = exp2f(SCL * sacc[i][r] - m_new);
        psum += p;
        pk[r] = (f16)p;
      }
      *(f16x4_t*)&Ps[r16 * 72 + i * 16 + q4] = pk;
    }
    psum += __shfl_xor(psum, 16, 64);
    psum += __shfl_xor(psum, 32, 64);
    lsum = lsum * alpha + psum;
    mrow = m_new;
#pragma unroll
    for (int id = 0; id < 4; id++) oacc[id] *= alpha;
    // O^T += Vt * P^T (P wave-private; DS in-order per wave)
#pragma unroll
    for (int s2 = 0; s2 < 2; s2++) {
      f16x8_t aV[4];
#pragma unroll
      for (int id = 0; id < 4; id++)
        aV[id] = *(const f16x8_t*)&Vs[cur][s2 * 2048 + (id * 16 + r16) * 32 + g8];
      const f16x8_t bP = *(const f16x8_t*)&Ps[r16 * 72 + s2 * 32 + g8];
#pragma unroll
      for (int id = 0; id < 4; id++)
        oacc[id] = __builtin_amdgcn_mfma_f32_16x16x32_f16(aV[id], bP, oacc[id], 0, 0, 0);
    }
    asm volatile("s_waitcnt lgkmcnt(0)" ::: "memory");  // buf[cur] reads done
    asm volatile("s_barrier" ::: "memory");             // all waves done with buf[cur]
    if (kt + 2 < AITERS) stage(kt + 2, cur);
  }
  // epilogue: attn_out[(b*256+q)*1024 + h*64 + d]
  const float inv = 1.0f / lsum;
  const int q = qt * 128 + wave * 16 + r16;
  const size_t rowbase = ((size_t)(b * N2 + q)) * DIMD + h * DH;
#pragma unroll
  for (int id = 0; id < 4; id++) {
    f16x4_t pk;
#pragma unroll
    for (int r = 0; r < 4; r++) pk[r] = (f16)(oacc[id][r] * inv);
    *(f16x4_t*)&attn_out[rowbase + id * 16 + q4] = pk;
  }
}

// ---------------------------------------------------------------------------
extern "C" void kernel_launch(void* const* d_in, const int* in_sizes, int n_in,
                              void* d_out, int out_size, void* d_ws, size_t ws_size,
                              hipStream_t stream) {
  const float* x     = (const float*)d_in[0];
  const float* lat   = (const float*)d_in[1];
  const float* shift = (const float*)d_in[2];
  const float* scale = (const float*)d_in[3];
  const float* ln1w  = (const float*)d_in[4];
  const float* ln1b  = (const float*)d_in[5];
  const float* ln2w  = (const float*)d_in[6];
  const float* ln2b  = (const float*)d_in[7];
  const float* Wq    = (const float*)d_in[8];
  const float* Wkv   = (const float*)d_in[9];
  const float* Wo    = (const float*)d_in[10];
  float* outp = (float*)d_out;

  char* ws = (char*)d_ws;
  f16* kv_in = (f16*)ws;                 ws += (size_t)MKV * DIMD * 2;          // 68 MB
  f16* Wq16  = (f16*)ws;                 ws += (size_t)1024 * 1024 * 2;         // 2 MB
  f16* Wkv16 = (f16*)ws;                 ws += (size_t)2048 * 1024 * 2;         // 4 MB
  f16* Wo16  = (f16*)ws;                 ws += (size_t)1024 * 1024 * 2;         // 2 MB
  f16* qbuf  = (f16*)ws;                 ws += (size_t)B_SZ * HEADS * N2 * DH * 2;   // 4 MB
  f16* kbuf  = (f16*)ws;                 ws += (size_t)B_SZ * HEADS * LTOT * DH * 2; // 68 MB
  f16* vbuf  = (f16*)ws;                 ws += (size_t)B_SZ * HEADS * LTOT * DH * 2; // 68 MB
  f16* aout  = (f16*)ws;                 ws += (size_t)B_SZ * N2 * DIMD * 2;         // 4 MB

  prep_kernel<<<dim3(MKV + 4096), dim3(256), 0, stream>>>(
      x, lat, shift, scale, ln1w, ln1b, ln2w, ln2b, Wq, Wkv, Wo,
      kv_in, Wq16, Wkv16, Wo16);
  gemm_pre<<<dim3(G0_BLOCKS + 128), dim3(256), 0, stream>>>(
      kv_in, Wkv16, Wq16, kbuf, vbuf, qbuf);
  attn_kernel<<<dim3(256), dim3(512), 0, stream>>>(qbuf, kbuf, vbuf, aout);
  gemm_out<<<dim3(8, 16), dim3(256), 0, stream>>>(aout, Wo16, outp);
}

// Round 7
// 538.063 us; speedup vs baseline: 1.1373x; 1.0033x over previous
//
#include <hip/hip_runtime.h>
#include <cstdint>
#include <cstddef>

#define B_SZ 8
#define N1 4096
#define N2 256
#define LTOT 4352          // N1 + N2
#define DIMD 1024
#define HEADS 16
#define DH 64
#define MKV (B_SZ * LTOT)  // 34816
#define ATILE 64
#define AITERS (LTOT / ATILE)  // 68
#define G0_BLOCKS 4352         // 272 mt x 16 nt
#define MT_PER_XCD 34          // 272 / 8

typedef _Float16 f16;
typedef f16 f16x4_t __attribute__((ext_vector_type(4)));
typedef f16 f16x8_t __attribute__((ext_vector_type(8)));
typedef float f32x4_t __attribute__((ext_vector_type(4)));

// async global -> LDS, 16B per lane. LDS dest is wave-uniform base + lane*16.
__device__ __forceinline__ void g2l16(const void* g, void* l) {
  __builtin_amdgcn_global_load_lds(
      (__attribute__((address_space(1))) void*)g,
      (__attribute__((address_space(3))) void*)l, 16, 0, 0);
}

// ---------------------------------------------------------------------------
// Kernel 1: prep = layernorm/modulation (blocks 0..MKV-1) + weight casts
// ---------------------------------------------------------------------------
__global__ __launch_bounds__(256) void prep_kernel(
    const float* __restrict__ x, const float* __restrict__ lat,
    const float* __restrict__ shift, const float* __restrict__ scale,
    const float* __restrict__ ln1w, const float* __restrict__ ln1b,
    const float* __restrict__ ln2w, const float* __restrict__ ln2b,
    const float* __restrict__ Wq, const float* __restrict__ Wkv,
    const float* __restrict__ Wo, f16* __restrict__ kv_in,
    f16* __restrict__ Wq16, f16* __restrict__ Wkv16, f16* __restrict__ Wo16) {
  const int bid = blockIdx.x;
  const int tid = threadIdx.x;
  if (bid >= MKV) {  // weight casts: 1024 f32 per block
    const int c = bid - MKV;
    const float* src;
    f16* dst;
    int off;
    if (c < 1024) { src = Wq; dst = Wq16; off = c; }
    else if (c < 3072) { src = Wkv; dst = Wkv16; off = c - 1024; }
    else { src = Wo; dst = Wo16; off = c - 3072; }
    const int i = off * 256 + tid;
    float4 v = ((const float4*)src)[i];
    f16x4_t o = {(f16)v.x, (f16)v.y, (f16)v.z, (f16)v.w};
    ((f16x4_t*)dst)[i] = o;
    return;
  }
  const int row = bid;
  const int b = row / LTOT;
  const int n = row - b * LTOT;
  const bool is_lat = (n >= N1);
  const float* src = is_lat ? (lat + (size_t)(b * N2 + (n - N1)) * DIMD)
                            : (x + (size_t)(b * N1 + n) * DIMD);
  float4 v = ((const float4*)src)[tid];
  float s = v.x + v.y + v.z + v.w;
  float s2 = v.x * v.x + v.y * v.y + v.z * v.z + v.w * v.w;
#pragma unroll
  for (int m = 1; m <= 32; m <<= 1) {
    s += __shfl_xor(s, m, 64);
    s2 += __shfl_xor(s2, m, 64);
  }
  __shared__ float red[8];
  const int wave = tid >> 6;
  if ((tid & 63) == 0) { red[wave * 2] = s; red[wave * 2 + 1] = s2; }
  __syncthreads();
  s = red[0] + red[2] + red[4] + red[6];
  s2 = red[1] + red[3] + red[5] + red[7];
  const float mean = s * (1.0f / DIMD);
  const float var = fmaxf(s2 * (1.0f / DIMD) - mean * mean, 0.0f);
  const float rstd = rsqrtf(var + 1e-5f);
  const float4 w4 = ((const float4*)(is_lat ? ln2w : ln1w))[tid];
  const float4 b4 = ((const float4*)(is_lat ? ln2b : ln1b))[tid];
  float y0 = (v.x - mean) * rstd * w4.x + b4.x;
  float y1 = (v.y - mean) * rstd * w4.y + b4.y;
  float y2 = (v.z - mean) * rstd * w4.z + b4.z;
  float y3 = (v.w - mean) * rstd * w4.w + b4.w;
  if (is_lat) {
    float4 sc = ((const float4*)(scale + (size_t)b * DIMD))[tid];
    float4 sh = ((const float4*)(shift + (size_t)b * DIMD))[tid];
    y0 = y0 * (1.0f + sc.x) + sh.x;
    y1 = y1 * (1.0f + sc.y) + sh.y;
    y2 = y2 * (1.0f + sc.z) + sh.z;
    y3 = y3 * (1.0f + sc.w) + sh.w;
  }
  f16x4_t o = {(f16)y0, (f16)y1, (f16)y2, (f16)y3};
  *(f16x4_t*)(kv_in + (size_t)row * DIMD + tid * 4) = o;
}

// ---------------------------------------------------------------------------
// Kernel 2: fused pre-attention GEMMs (kv + q) in ONE dispatch.
// 128x128 tiles, BK=32, 16x16x32 f16 MFMA, XCD-swizzled kv blocks (R6-proven:
// FETCH 150 MB). NEW: double-buffered LDS K-loop with raw vmcnt(4)/s_barrier
// (AITER pattern) — tile k's loads issued 2 iters ago, so the wait is ~free
// and tile k+1 stays in flight across the barrier (no vmcnt(0) drain).
// ---------------------------------------------------------------------------
__global__ __launch_bounds__(256, 4) void gemm_pre(
    const f16* __restrict__ kv_in, const f16* __restrict__ Wkv16,
    const f16* __restrict__ Wq16, f16* __restrict__ kbuf,
    f16* __restrict__ vbuf, f16* __restrict__ qbuf) {
  const int id = blockIdx.x;
  const bool is_kv = (id < G0_BLOCKS);
  int mt, nt;
  const f16 *Abase, *Bbase;
  if (is_kv) {
    const int xcd = id & 7, l = id >> 3;
    mt = xcd * MT_PER_XCD + (l >> 4);
    nt = l & 15;
    Abase = kv_in + (size_t)mt * 128 * DIMD;
    Bbase = Wkv16 + (size_t)nt * 128 * DIMD;
  } else {
    const int id2 = id - G0_BLOCKS;
    mt = id2 >> 3;  // 0..15
    nt = id2 & 7;
    const int bb = mt >> 1;
    Abase = kv_in + ((size_t)(bb * LTOT + N1 + (mt & 1) * 128)) * DIMD;
    Bbase = Wq16 + (size_t)nt * 128 * DIMD;
  }
  __shared__ alignas(16) f16 As[2][128 * 32];
  __shared__ alignas(16) f16 Bs[2][128 * 32];
  const int tid = threadIdx.x;
  const int wave = tid >> 6, lane = tid & 63;
  const int wm = (wave & 1) * 64, wn = (wave >> 1) * 64;
  const int lrow = lane >> 2, lcol = (lane & 3) * 8;
  const int r16 = lane & 15, g8 = (lane >> 4) * 8, q4 = (lane >> 4) * 4;
  f32x4_t acc[4][4] = {};

  // 4 g2l16 per wave per tile
  auto stage = [&](int k0, int buf) {
    g2l16(Abase + (size_t)(wave * 16 + lrow) * DIMD + k0 + lcol, &As[buf][(wave * 16) * 32]);
    g2l16(Abase + (size_t)(64 + wave * 16 + lrow) * DIMD + k0 + lcol, &As[buf][(64 + wave * 16) * 32]);
    g2l16(Bbase + (size_t)(wave * 16 + lrow) * DIMD + k0 + lcol, &Bs[buf][(wave * 16) * 32]);
    g2l16(Bbase + (size_t)(64 + wave * 16 + lrow) * DIMD + k0 + lcol, &Bs[buf][(64 + wave * 16) * 32]);
  };
  auto body = [&](int kt, int cur) {
    if (kt < 31) asm volatile("s_waitcnt vmcnt(4)" ::: "memory");  // tile kt landed
    else         asm volatile("s_waitcnt vmcnt(0)" ::: "memory");  // final tile
    asm volatile("s_barrier" ::: "memory");
    f16x8_t a[4], bf[4];
#pragma unroll
    for (int i = 0; i < 4; i++)
      a[i] = *(const f16x8_t*)&As[cur][(wm + i * 16 + r16) * 32 + g8];
#pragma unroll
    for (int j = 0; j < 4; j++)
      bf[j] = *(const f16x8_t*)&Bs[cur][(wn + j * 16 + r16) * 32 + g8];
#pragma unroll
    for (int i = 0; i < 4; i++)
#pragma unroll
      for (int j = 0; j < 4; j++)
        acc[i][j] = __builtin_amdgcn_mfma_f32_16x16x32_f16(a[i], bf[j], acc[i][j], 0, 0, 0);
    asm volatile("s_waitcnt lgkmcnt(0)" ::: "memory");  // buf[cur] reads done
    asm volatile("s_barrier" ::: "memory");
    if (kt + 2 < 32) stage((kt + 2) * 32, cur);  // refill buf[cur]
  };
  stage(0, 0);
  stage(32, 1);
#pragma unroll 1
  for (int kt = 0; kt < 32; kt += 2) { body(kt, 0); body(kt + 1, 1); }

  if (is_kv) {
    const int m0 = mt * 128;
    const int b = m0 / LTOT;
    const int n0 = m0 - b * LTOT;
    const int e0 = nt * 128;
    if (e0 < 1024) {  // k half: ((b*16+h)*4352 + n)*64 + d
#pragma unroll
      for (int i = 0; i < 4; i++) {
        const int n_base = n0 + wm + i * 16 + q4;
#pragma unroll
        for (int j = 0; j < 4; j++) {
          const int e = e0 + wn + j * 16 + r16;
          const int h = e >> 6, d = e & 63;
          const size_t base = ((size_t)(b * HEADS + h) * LTOT);
#pragma unroll
          for (int r = 0; r < 4; r++)
            kbuf[(base + n_base + r) * DH + d] = (f16)acc[i][j][r];
        }
      }
    } else {  // v half, transposed: ((b*16+h)*64 + d)*4352 + n
      const int e0v = e0 - 1024;
#pragma unroll
      for (int i = 0; i < 4; i++) {
        const int n_base = n0 + wm + i * 16 + q4;
#pragma unroll
        for (int j = 0; j < 4; j++) {
          const int e = e0v + wn + j * 16 + r16;
          const int h = e >> 6, d = e & 63;
          f16x4_t pk = {(f16)acc[i][j][0], (f16)acc[i][j][1],
                        (f16)acc[i][j][2], (f16)acc[i][j][3]};
          *(f16x4_t*)&vbuf[((size_t)(b * HEADS + h) * DH + d) * LTOT + n_base] = pk;
        }
      }
    }
  } else {  // q: ((b*16+h)*256 + n)*64 + d
    const int b = mt >> 1;
#pragma unroll
    for (int i = 0; i < 4; i++) {
      const int n_base = (mt & 1) * 128 + wm + i * 16 + q4;
#pragma unroll
      for (int j = 0; j < 4; j++) {
        const int e = nt * 128 + wn + j * 16 + r16;
        const int h = e >> 6, d = e & 63;
#pragma unroll
        for (int r = 0; r < 4; r++)
          qbuf[((size_t)(b * HEADS + h) * N2 + n_base + r) * DH + d] = (f16)acc[i][j][r];
      }
    }
  }
}

// ---------------------------------------------------------------------------
// Kernel 3: out GEMM -> f32 d_out. 128x64 tiles (256 blocks = 1/CU, 2x the
// R6 parallelism) + same dbuf/vmcnt pipelined K-loop (critical here: with 1
// block/CU there is NO inter-block overlap to hide a vmcnt(0) drain).
// ---------------------------------------------------------------------------
__global__ __launch_bounds__(256) void gemm_out(
    const f16* __restrict__ A0, const f16* __restrict__ BT,
    float* __restrict__ outp) {
  const int id = blockIdx.x;
  const int mt = id >> 4, nt = id & 15;
  const f16* Abase = A0 + (size_t)mt * 128 * DIMD;
  const f16* Bbase = BT + (size_t)nt * 64 * DIMD;
  __shared__ alignas(16) f16 As[2][128 * 32];
  __shared__ alignas(16) f16 Bs[2][64 * 32];
  const int tid = threadIdx.x;
  const int wave = tid >> 6, lane = tid & 63;
  const int wm = (wave & 1) * 64, wn = (wave >> 1) * 32;
  const int lrow = lane >> 2, lcol = (lane & 3) * 8;
  const int r16 = lane & 15, g8 = (lane >> 4) * 8, q4 = (lane >> 4) * 4;
  f32x4_t acc[4][2] = {};

  // 3 g2l16 per wave per tile (A 2 chunks, B 1 chunk)
  auto stage = [&](int k0, int buf) {
    g2l16(Abase + (size_t)(wave * 16 + lrow) * DIMD + k0 + lcol, &As[buf][(wave * 16) * 32]);
    g2l16(Abase + (size_t)(64 + wave * 16 + lrow) * DIMD + k0 + lcol, &As[buf][(64 + wave * 16) * 32]);
    g2l16(Bbase + (size_t)(wave * 16 + lrow) * DIMD + k0 + lcol, &Bs[buf][(wave * 16) * 32]);
  };
  auto body = [&](int kt, int cur) {
    if (kt < 31) asm volatile("s_waitcnt vmcnt(3)" ::: "memory");
    else         asm volatile("s_waitcnt vmcnt(0)" ::: "memory");
    asm volatile("s_barrier" ::: "memory");
    f16x8_t a[4], bf[2];
#pragma unroll
    for (int i = 0; i < 4; i++)
      a[i] = *(const f16x8_t*)&As[cur][(wm + i * 16 + r16) * 32 + g8];
#pragma unroll
    for (int j = 0; j < 2; j++)
      bf[j] = *(const f16x8_t*)&Bs[cur][(wn + j * 16 + r16) * 32 + g8];
#pragma unroll
    for (int i = 0; i < 4; i++)
#pragma unroll
      for (int j = 0; j < 2; j++)
        acc[i][j] = __builtin_amdgcn_mfma_f32_16x16x32_f16(a[i], bf[j], acc[i][j], 0, 0, 0);
    asm volatile("s_waitcnt lgkmcnt(0)" ::: "memory");
    asm volatile("s_barrier" ::: "memory");
    if (kt + 2 < 32) stage((kt + 2) * 32, cur);
  };
  stage(0, 0);
  stage(32, 1);
#pragma unroll 1
  for (int kt = 0; kt < 32; kt += 2) { body(kt, 0); body(kt + 1, 1); }

  const int m0 = mt * 128, n0 = nt * 64;
#pragma unroll
  for (int i = 0; i < 4; i++) {
#pragma unroll
    for (int j = 0; j < 2; j++) {
      const int col = n0 + wn + j * 16 + r16;
#pragma unroll
      for (int r = 0; r < 4; r++)
        outp[(size_t)(m0 + wm + i * 16 + q4 + r) * DIMD + col] = acc[i][j][r];
    }
  }
}

// ---------------------------------------------------------------------------
// Kernel 4: flash attention — 512 threads (8 waves), K-tile 64, depth-2 async
// K/V double-buffer with raw vmcnt/s_barrier. (512,2): 2 blocks/CU. FROZEN.
// ---------------------------------------------------------------------------
__global__ __launch_bounds__(512, 2) void attn_kernel(
    const f16* __restrict__ qbuf, const f16* __restrict__ kbuf,
    const f16* __restrict__ vbuf, f16* __restrict__ attn_out) {
  const int bh = blockIdx.x >> 1;
  const int qt = blockIdx.x & 1;
  const int b = bh >> 4, h = bh & 15;
  const f16* qg = qbuf + ((size_t)bh * N2 + qt * 128) * DH;
  const f16* kg = kbuf + (size_t)bh * LTOT * DH;
  const f16* vg = vbuf + (size_t)bh * DH * LTOT;

  __shared__ alignas(16) f16 Ks[2][4096];  // 2 bufs x (2 d-panels x 64k x 32)
  __shared__ alignas(16) f16 Vs[2][4096];  // 2 bufs x (2 k-panels x 64d x 32)
  __shared__ alignas(16) f16 QP[9216];     // Q (8192, prologue) / P (per-wave)

  const int tid = threadIdx.x, wave = tid >> 6, lane = tid & 63;
  const int lrow = lane >> 2, lcol = (lane & 3) * 8;
  const int r16 = lane & 15, g8 = (lane >> 4) * 8, q4 = (lane >> 4) * 4;
  f16* Ps = &QP[wave * 1152];  // 16 q-rows x 72 halves, wave-private

  // prologue: stage Q (2 chunks/wave)
#pragma unroll
  for (int i = 0; i < 2; i++) {
    const int c = wave * 2 + i, s = c >> 3, rb = (c & 7) * 16;
    g2l16(qg + (size_t)(rb + lrow) * DH + s * 32 + lcol, &QP[s * 4096 + rb * 32]);
  }
  auto stage = [&](int kt, int buf) {
    const int s = wave >> 2, rb = (wave & 3) * 16;
    g2l16(kg + (size_t)(kt * ATILE + rb + lrow) * DH + s * 32 + lcol,
          &Ks[buf][s * 2048 + rb * 32]);
    g2l16(vg + (size_t)(rb + lrow) * LTOT + kt * ATILE + s * 32 + lcol,
          &Vs[buf][s * 2048 + rb * 32]);
  };
  stage(0, 0);
  stage(1, 1);
  asm volatile("s_waitcnt vmcnt(4)" ::: "memory");  // Q (oldest 2) landed
  asm volatile("s_barrier" ::: "memory");
  f16x8_t bQ[2];
#pragma unroll
  for (int s = 0; s < 2; s++)
    bQ[s] = *(const f16x8_t*)&QP[s * 4096 + (wave * 16 + r16) * 32 + g8];
  asm volatile("s_waitcnt lgkmcnt(0)" ::: "memory");  // bQ in regs before P overlays Q

  f32x4_t oacc[4] = {};
  float mrow = -1e30f, lsum = 0.0f;
  const float SCL = 0.125f * 1.44269504089f;  // attn_scale^2 * log2(e)

  for (int kt = 0; kt < AITERS; kt++) {
    const int cur = kt & 1;
    asm volatile("s_waitcnt vmcnt(2)" ::: "memory");  // buf[cur] landed; next in flight
    asm volatile("s_barrier" ::: "memory");
    f32x4_t sacc[4] = {};
#pragma unroll
    for (int s = 0; s < 2; s++) {
      f16x8_t aK[4];
#pragma unroll
      for (int i = 0; i < 4; i++)
        aK[i] = *(const f16x8_t*)&Ks[cur][s * 2048 + (i * 16 + r16) * 32 + g8];
#pragma unroll
      for (int i = 0; i < 4; i++)
        sacc[i] = __builtin_amdgcn_mfma_f32_16x16x32_f16(aK[i], bQ[s], sacc[i], 0, 0, 0);
    }
    float vmax = -1e30f;
#pragma unroll
    for (int i = 0; i < 4; i++)
#pragma unroll
      for (int r = 0; r < 4; r++) vmax = fmaxf(vmax, sacc[i][r]);
    vmax = fmaxf(vmax, __shfl_xor(vmax, 16, 64));
    vmax = fmaxf(vmax, __shfl_xor(vmax, 32, 64));
    const float m_new = fmaxf(mrow, SCL * vmax);
    const float alpha = exp2f(mrow - m_new);
    float psum = 0.0f;
#pragma unroll
    for (int i = 0; i < 4; i++) {
      f16x4_t pk;
#pragma unroll
      for (int r = 0; r < 4; r++) {
        const float p = exp2f(SCL * sacc[i][r] - m_new);
        psum += p;
        pk[r] = (f16)p;
      }
      *(f16x4_t*)&Ps[r16 * 72 + i * 16 + q4] = pk;
    }
    psum += __shfl_xor(psum, 16, 64);
    psum += __shfl_xor(psum, 32, 64);
    lsum = lsum * alpha + psum;
    mrow = m_new;
#pragma unroll
    for (int id = 0; id < 4; id++) oacc[id] *= alpha;
#pragma unroll
    for (int s2 = 0; s2 < 2; s2++) {
      f16x8_t aV[4];
#pragma unroll
      for (int id = 0; id < 4; id++)
        aV[id] = *(const f16x8_t*)&Vs[cur][s2 * 2048 + (id * 16 + r16) * 32 + g8];
      const f16x8_t bP = *(const f16x8_t*)&Ps[r16 * 72 + s2 * 32 + g8];
#pragma unroll
      for (int id = 0; id < 4; id++)
        oacc[id] = __builtin_amdgcn_mfma_f32_16x16x32_f16(aV[id], bP, oacc[id], 0, 0, 0);
    }
    asm volatile("s_waitcnt lgkmcnt(0)" ::: "memory");
    asm volatile("s_barrier" ::: "memory");
    if (kt + 2 < AITERS) stage(kt + 2, cur);
  }
  const float inv = 1.0f / lsum;
  const int q = qt * 128 + wave * 16 + r16;
  const size_t rowbase = ((size_t)(b * N2 + q)) * DIMD + h * DH;
#pragma unroll
  for (int id = 0; id < 4; id++) {
    f16x4_t pk;
#pragma unroll
    for (int r = 0; r < 4; r++) pk[r] = (f16)(oacc[id][r] * inv);
    *(f16x4_t*)&attn_out[rowbase + id * 16 + q4] = pk;
  }
}

// ---------------------------------------------------------------------------
extern "C" void kernel_launch(void* const* d_in, const int* in_sizes, int n_in,
                              void* d_out, int out_size, void* d_ws, size_t ws_size,
                              hipStream_t stream) {
  const float* x     = (const float*)d_in[0];
  const float* lat   = (const float*)d_in[1];
  const float* shift = (const float*)d_in[2];
  const float* scale = (const float*)d_in[3];
  const float* ln1w  = (const float*)d_in[4];
  const float* ln1b  = (const float*)d_in[5];
  const float* ln2w  = (const float*)d_in[6];
  const float* ln2b  = (const float*)d_in[7];
  const float* Wq    = (const float*)d_in[8];
  const float* Wkv   = (const float*)d_in[9];
  const float* Wo    = (const float*)d_in[10];
  float* outp = (float*)d_out;

  char* ws = (char*)d_ws;
  f16* kv_in = (f16*)ws;                 ws += (size_t)MKV * DIMD * 2;          // 68 MB
  f16* Wq16  = (f16*)ws;                 ws += (size_t)1024 * 1024 * 2;         // 2 MB
  f16* Wkv16 = (f16*)ws;                 ws += (size_t)2048 * 1024 * 2;         // 4 MB
  f16* Wo16  = (f16*)ws;                 ws += (size_t)1024 * 1024 * 2;         // 2 MB
  f16* qbuf  = (f16*)ws;                 ws += (size_t)B_SZ * HEADS * N2 * DH * 2;   // 4 MB
  f16* kbuf  = (f16*)ws;                 ws += (size_t)B_SZ * HEADS * LTOT * DH * 2; // 68 MB
  f16* vbuf  = (f16*)ws;                 ws += (size_t)B_SZ * HEADS * LTOT * DH * 2; // 68 MB
  f16* aout  = (f16*)ws;                 ws += (size_t)B_SZ * N2 * DIMD * 2;         // 4 MB

  prep_kernel<<<dim3(MKV + 4096), dim3(256), 0, stream>>>(
      x, lat, shift, scale, ln1w, ln1b, ln2w, ln2b, Wq, Wkv, Wo,
      kv_in, Wq16, Wkv16, Wo16);
  gemm_pre<<<dim3(G0_BLOCKS + 128), dim3(256), 0, stream>>>(
      kv_in, Wkv16, Wq16, kbuf, vbuf, qbuf);
  attn_kernel<<<dim3(256), dim3(512), 0, stream>>>(qbuf, kbuf, vbuf, aout);
  gemm_out<<<dim3(256), dim3(256), 0, stream>>>(aout, Wo16, outp);
}